// Round 1
// baseline (1137.788 us; speedup 1.0000x reference)
//
#include <hip/hip_runtime.h>
#include <hip/hip_bf16.h>
#include <cstdint>

// HaloAttention: B=4, H=W=128, C=256, 8 heads, kd=32, block=8, halo=2, kvk=12.
// Pipeline: [gemm Q][gemm KV] -> [attention per (b,block,head)] -> [gemm out].
// Intermediates stored bf16 in d_ws: Q 32MB @0, KV 64MB @32MB, attnOut 32MB @96MB.

#define KVK 12
#define NKEYS 144

typedef unsigned int u32;
typedef unsigned short u16;

__device__ __forceinline__ float bflo(u32 w) { return __uint_as_float(w << 16); }
__device__ __forceinline__ float bfhi(u32 w) { return __uint_as_float(w & 0xffff0000u); }
__device__ __forceinline__ float bf2f(u16 u) { return __uint_as_float(((u32)u) << 16); }
__device__ __forceinline__ u16 f2bf(float f) {
    u32 x = __float_as_uint(f);
    return (u16)((x + 0x7fffu + ((x >> 16) & 1u)) >> 16);
}

// ---------------- GEMM: C[M x N] = A[M x 256] * W[256 x N] ----------------
// A_BF16: A is bf16 (else f32). C_BF16: C is bf16 (else f32).
template <int A_BF16, int C_BF16>
__global__ __launch_bounds__(256) void gemm_kernel(const void* __restrict__ Av,
                                                   const float* __restrict__ W,
                                                   void* __restrict__ Cv, int N) {
    __shared__ float As[64][33];
    __shared__ float Bs[32][65];
    const int t = threadIdx.x;
    const int m0 = blockIdx.x * 64;
    const int n0 = blockIdx.y * 64;
    const int ty = t >> 4, tx = t & 15;
    float acc[4][4] = {};
    const float* Af = (const float*)Av;
    const u16* Ab = (const u16*)Av;

    for (int k0 = 0; k0 < 256; k0 += 32) {
        // A tile 64x32 (coalesced: 32 consecutive threads = one row chunk)
        #pragma unroll
        for (int idx = t; idx < 2048; idx += 256) {
            int r = idx >> 5, c = idx & 31;
            long off = (long)(m0 + r) * 256 + k0 + c;
            As[r][c] = A_BF16 ? bf2f(Ab[off]) : Af[off];
        }
        // W tile 32x64
        #pragma unroll
        for (int idx = t; idx < 2048; idx += 256) {
            int r = idx >> 6, c = idx & 63;
            Bs[r][c] = W[(long)(k0 + r) * N + n0 + c];
        }
        __syncthreads();
        #pragma unroll
        for (int kk = 0; kk < 32; ++kk) {
            float a[4], bb[4];
            #pragma unroll
            for (int i = 0; i < 4; ++i) a[i] = As[ty * 4 + i][kk];
            #pragma unroll
            for (int j = 0; j < 4; ++j) bb[j] = Bs[kk][tx * 4 + j];
            #pragma unroll
            for (int i = 0; i < 4; ++i)
                #pragma unroll
                for (int j = 0; j < 4; ++j) acc[i][j] += a[i] * bb[j];
        }
        __syncthreads();
    }
    #pragma unroll
    for (int i = 0; i < 4; ++i) {
        long row = m0 + ty * 4 + i;
        long base = row * N + n0 + tx * 4;
        if (C_BF16) {
            ushort4 o;
            o.x = f2bf(acc[i][0]); o.y = f2bf(acc[i][1]);
            o.z = f2bf(acc[i][2]); o.w = f2bf(acc[i][3]);
            *reinterpret_cast<ushort4*>((u16*)Cv + base) = o;
        } else {
            float4 o = make_float4(acc[i][0], acc[i][1], acc[i][2], acc[i][3]);
            *reinterpret_cast<float4*>((float*)Cv + base) = o;
        }
    }
}

// ---------------- Attention ----------------
// grid = 4 * 16 * 16 * 8 blocks; block = (b, by, bx, head n); 256 threads.
__global__ __launch_bounds__(256) void attn_kernel(const u16* __restrict__ Qb,
                                                   const u16* __restrict__ KVb,
                                                   const float* __restrict__ emb_h,
                                                   const float* __restrict__ emb_w,
                                                   u16* __restrict__ Ob) {
    __shared__ u16 Qs[64][32];
    __shared__ u16 Ks[NKEYS][32];
    __shared__ u16 Vs[NKEYS][32];
    __shared__ float eh[23][32];
    __shared__ float ew[23][32];
    __shared__ float relh[64][13];
    __shared__ float relw[64][13];
    __shared__ float sc[64][145];

    const int gblk = blockIdx.x;
    const int n = gblk & 7;
    const int bx = (gblk >> 3) & 15;
    const int by = (gblk >> 7) & 15;
    const int b = gblk >> 11;
    const int t = threadIdx.x;

    // ---- load Q tile: 64 queries x 32 dims (bf16), 8 elems/thread ----
    {
        int q = t >> 2, d0 = (t & 3) * 8;
        int qi = q >> 3, qj = q & 7;
        long row = ((long)b * 128 + by * 8 + qi) * 128 + bx * 8 + qj;
        *reinterpret_cast<uint4*>(&Qs[q][d0]) =
            *reinterpret_cast<const uint4*>(Qb + row * 256 + n * 32 + d0);
    }
    // ---- load K/V window: 144 keys x 64 ch, zero-padded halo ----
    for (int u = t; u < NKEYS * 8; u += 256) {
        int kk = u >> 3, part = u & 7;
        int ky = kk / KVK, kx = kk % KVK;
        int gy = by * 8 + ky - 2, gx = bx * 8 + kx - 2;
        uint4 val = make_uint4(0u, 0u, 0u, 0u);
        if (gy >= 0 && gy < 128 && gx >= 0 && gx < 128) {
            long row = ((long)b * 128 + gy) * 128 + gx;
            val = *reinterpret_cast<const uint4*>(KVb + row * 512 + n * 64 + part * 8);
        }
        if (part < 4) *reinterpret_cast<uint4*>(&Ks[kk][part * 8]) = val;
        else         *reinterpret_cast<uint4*>(&Vs[kk][(part - 4) * 8]) = val;
    }
    // ---- load pos embeddings transposed: e[r][d] = emb[d*23 + r] ----
    for (int idx = t; idx < 736; idx += 256) {
        int d = idx / 23, r = idx % 23;
        eh[r][d] = emb_h[idx];
        ew[r][d] = emb_w[idx];
    }
    __syncthreads();

    // ---- relative logits: relh[q][ky] = q . emb_h[:, ky-qi+11]; same for w ----
    #pragma unroll
    for (int u = t; u < 1536; u += 256) {
        int which = (u >= 768);
        int v = which ? u - 768 : u;
        int q = v / 12, kpos = v - 12 * (v / 12);
        int qi = q >> 3, qj = q & 7;
        int r = kpos - (which ? qj : qi) + 11;
        const float* e = which ? &ew[r][0] : &eh[r][0];
        float s = 0.f;
        #pragma unroll
        for (int d = 0; d < 32; ++d) s += bf2f(Qs[q][d]) * e[d];
        if (which) relw[q][kpos] = s;
        else       relh[q][kpos] = s;
    }
    __syncthreads();

    // ---- scores + softmax: thread (q, g) owns keys k = g*36 .. g*36+35 ----
    const int q = t >> 2, gg = t & 3;
    float qv[32];
    {
        const uint4* qp = reinterpret_cast<const uint4*>(&Qs[q][0]);
        #pragma unroll
        for (int c = 0; c < 4; ++c) {
            uint4 q4 = qp[c];
            qv[8 * c + 0] = bflo(q4.x); qv[8 * c + 1] = bfhi(q4.x);
            qv[8 * c + 2] = bflo(q4.y); qv[8 * c + 3] = bfhi(q4.y);
            qv[8 * c + 4] = bflo(q4.z); qv[8 * c + 5] = bfhi(q4.z);
            qv[8 * c + 6] = bflo(q4.w); qv[8 * c + 7] = bfhi(q4.w);
        }
    }
    const float scale = 0.17677669529663687f;  // 1/sqrt(32)
    float sreg[36];
    float mx = -1e30f;
    #pragma unroll
    for (int j = 0; j < 36; ++j) {
        int k = gg * 36 + j;
        float s = 0.f;
        const uint4* kp = reinterpret_cast<const uint4*>(&Ks[k][0]);
        #pragma unroll
        for (int c = 0; c < 4; ++c) {
            uint4 k4 = kp[c];
            s += bflo(k4.x) * qv[8 * c + 0]; s += bfhi(k4.x) * qv[8 * c + 1];
            s += bflo(k4.y) * qv[8 * c + 2]; s += bfhi(k4.y) * qv[8 * c + 3];
            s += bflo(k4.z) * qv[8 * c + 4]; s += bfhi(k4.z) * qv[8 * c + 5];
            s += bflo(k4.w) * qv[8 * c + 6]; s += bfhi(k4.w) * qv[8 * c + 7];
        }
        int ky = k / KVK, kx = k - KVK * ky;
        s = s * scale + relh[q][ky] + relw[q][kx];
        sreg[j] = s;
        mx = fmaxf(mx, s);
    }
    mx = fmaxf(mx, __shfl_xor(mx, 1));
    mx = fmaxf(mx, __shfl_xor(mx, 2));
    float sum = 0.f;
    #pragma unroll
    for (int j = 0; j < 36; ++j) {
        sreg[j] = __expf(sreg[j] - mx);
        sum += sreg[j];
    }
    sum += __shfl_xor(sum, 1);
    sum += __shfl_xor(sum, 2);
    const float inv = 1.0f / sum;
    #pragma unroll
    for (int j = 0; j < 36; ++j) sc[q][gg * 36 + j] = sreg[j] * inv;
    __syncthreads();

    // ---- PV: thread (q, g) computes out dims d = g*8 .. g*8+7 ----
    float acc8[8] = {};
    const int d0 = gg * 8;
    for (int k = 0; k < NKEYS; ++k) {
        float p = sc[q][k];
        uint4 v4 = *reinterpret_cast<const uint4*>(&Vs[k][d0]);
        acc8[0] += p * bflo(v4.x); acc8[1] += p * bfhi(v4.x);
        acc8[2] += p * bflo(v4.y); acc8[3] += p * bfhi(v4.y);
        acc8[4] += p * bflo(v4.z); acc8[5] += p * bfhi(v4.z);
        acc8[6] += p * bflo(v4.w); acc8[7] += p * bfhi(v4.w);
    }
    {
        int qi = q >> 3, qj = q & 7;
        long row = ((long)b * 128 + by * 8 + qi) * 128 + bx * 8 + qj;
        ushort4 o0, o1;
        o0.x = f2bf(acc8[0]); o0.y = f2bf(acc8[1]); o0.z = f2bf(acc8[2]); o0.w = f2bf(acc8[3]);
        o1.x = f2bf(acc8[4]); o1.y = f2bf(acc8[5]); o1.z = f2bf(acc8[6]); o1.w = f2bf(acc8[7]);
        *reinterpret_cast<ushort4*>(Ob + row * 256 + n * 32 + d0) = o0;
        *reinterpret_cast<ushort4*>(Ob + row * 256 + n * 32 + d0 + 4) = o1;
    }
}

extern "C" void kernel_launch(void* const* d_in, const int* in_sizes, int n_in,
                              void* d_out, int out_size, void* d_ws, size_t ws_size,
                              hipStream_t stream) {
    const float* x     = (const float*)d_in[0];
    const float* w_q   = (const float*)d_in[1];
    const float* w_kv  = (const float*)d_in[2];
    const float* w_out = (const float*)d_in[3];
    const float* emb_h = (const float*)d_in[4];
    const float* emb_w = (const float*)d_in[5];
    float* out = (float*)d_out;

    char* ws = (char*)d_ws;
    u16* Qb  = (u16*)(ws);                    // 65536 x 256 bf16 = 32MB
    u16* KVb = (u16*)(ws + (size_t)33554432); // 65536 x 512 bf16 = 64MB
    u16* Ob  = (u16*)(ws + (size_t)100663296);// 65536 x 256 bf16 = 32MB

    dim3 blk(256);
    gemm_kernel<0, 1><<<dim3(1024, 4), blk, 0, stream>>>(x, w_q, Qb, 256);
    gemm_kernel<0, 1><<<dim3(1024, 8), blk, 0, stream>>>(x, w_kv, KVb, 512);
    attn_kernel<<<dim3(4 * 16 * 16 * 8), blk, 0, stream>>>(Qb, KVb, emb_h, emb_w, Ob);
    gemm_kernel<1, 0><<<dim3(1024, 4), blk, 0, stream>>>(Ob, w_out, out, 256);
}

// Round 2
// 460.533 us; speedup vs baseline: 2.4706x; 2.4706x over previous
//
#include <hip/hip_runtime.h>
#include <hip/hip_bf16.h>
#include <cstdint>

// HaloAttention: B=4, H=W=128, C=256, 8 heads, kd=32, block=8, halo=2, kvk=12.
// Pipeline: conv(x->bf16) + transpose(weights->bf16) ->
//   [mfma gemm Q][mfma gemm KV] -> [attention] -> [mfma gemm out].
// Buffers: xb (32MB) + Qb (32MB) in d_out (dead before final gemm writes it);
//          KVb 64MB @ws+0, Ob 32MB @ws+64MB, wT @ws+96MB.

#define KVK 12
#define NKEYS 144

typedef unsigned int u32;
typedef unsigned short u16;
typedef __attribute__((ext_vector_type(8))) __bf16 bf16x8;
typedef __attribute__((ext_vector_type(4))) float f32x4;

__device__ __forceinline__ float bflo(u32 w) { return __uint_as_float(w << 16); }
__device__ __forceinline__ float bfhi(u32 w) { return __uint_as_float(w & 0xffff0000u); }
__device__ __forceinline__ float bf2f(u16 u) { return __uint_as_float(((u32)u) << 16); }
__device__ __forceinline__ u16 f2bf(float f) {
    u32 x = __float_as_uint(f);
    return (u16)((x + 0x7fffu + ((x >> 16) & 1u)) >> 16);
}
__device__ __forceinline__ u32 pack2(float lo, float hi) {
    return (u32)f2bf(lo) | ((u32)f2bf(hi) << 16);
}

__device__ __forceinline__ void gload16(const void* g, void* l) {
    __builtin_amdgcn_global_load_lds(
        (const __attribute__((address_space(1))) void*)g,
        (__attribute__((address_space(3))) void*)l, 16, 0, 0);
}

// ---------------- x (f32) -> bf16, 8 elems/thread ----------------
__global__ __launch_bounds__(256) void conv_bf16(const float* __restrict__ in,
                                                 u16* __restrict__ out) {
    int i = blockIdx.x * 256 + threadIdx.x;
    const float4* p = reinterpret_cast<const float4*>(in) + (long)i * 2;
    float4 a = p[0], b = p[1];
    uint4 o;
    o.x = pack2(a.x, a.y); o.y = pack2(a.z, a.w);
    o.z = pack2(b.x, b.y); o.w = pack2(b.z, b.w);
    reinterpret_cast<uint4*>(out)[i] = o;
}

// ---------------- W[256 x N] f32 -> WT[N x 256] bf16 ----------------
__global__ __launch_bounds__(256) void tr_bf16(const float* __restrict__ w,
                                               u16* __restrict__ wt, int N) {
    int idx = blockIdx.x * 256 + threadIdx.x;  // idx = n*256 + k
    int n = idx >> 8, k = idx & 255;
    wt[idx] = f2bf(w[(long)k * N + n]);
}

// ---------------- MFMA GEMM: C[M x N] = A[M x 256] * BT[N x 256]^T ----------
// 128x128 tile, BK=32, 4 waves of 64x64 (4x4 16x16x32 fragments). m97 structure.
template <int C_BF16>
__global__ __launch_bounds__(256) void mfma_gemm(const u16* __restrict__ A,
                                                 const u16* __restrict__ BT,
                                                 void* __restrict__ Cv, int N) {
    __shared__ u16 As[4096];  // [128 rows][32 k] linear
    __shared__ u16 Bs[4096];  // [128 cols][32 k] linear
    const int t = threadIdx.x;
    const int w = t >> 6, lane = t & 63;
    const long m0 = (long)blockIdx.x * 128;
    const long n0 = (long)blockIdx.y * 128;
    const int wr = w >> 1, wc = w & 1;
    const int r = lane & 15, g = lane >> 4;

    f32x4 acc[4][4];
    #pragma unroll
    for (int i = 0; i < 4; ++i)
        #pragma unroll
        for (int j = 0; j < 4; ++j) acc[i][j] = (f32x4){0.f, 0.f, 0.f, 0.f};

    // staging: round q in {0,1}: linear 8-elem unit u = w*128 + q*64 + lane
    const int u0 = w * 128 + lane;
    const int row0 = u0 >> 2, cs0 = (u0 & 3) * 8;
    const int u1 = u0 + 64;
    const int row1 = u1 >> 2, cs1 = (u1 & 3) * 8;
    const u16* Ag0 = A + (m0 + row0) * 256 + cs0;
    const u16* Ag1 = A + (m0 + row1) * 256 + cs1;
    const u16* Bg0 = BT + (n0 + row0) * 256 + cs0;
    const u16* Bg1 = BT + (n0 + row1) * 256 + cs1;
    u16* AsW = &As[w * 1024];
    u16* BsW = &Bs[w * 1024];

    for (int k0 = 0; k0 < 256; k0 += 32) {
        gload16(Ag0 + k0, AsW);
        gload16(Ag1 + k0, AsW + 512);
        gload16(Bg0 + k0, BsW);
        gload16(Bg1 + k0, BsW + 512);
        __syncthreads();
        bf16x8 a[4], b[4];
        #pragma unroll
        for (int i = 0; i < 4; ++i)
            a[i] = *reinterpret_cast<const bf16x8*>(&As[(wr * 64 + i * 16 + r) * 32 + g * 8]);
        #pragma unroll
        for (int j = 0; j < 4; ++j)
            b[j] = *reinterpret_cast<const bf16x8*>(&Bs[(wc * 64 + j * 16 + r) * 32 + g * 8]);
        #pragma unroll
        for (int i = 0; i < 4; ++i)
            #pragma unroll
            for (int j = 0; j < 4; ++j)
                acc[i][j] = __builtin_amdgcn_mfma_f32_16x16x32_bf16(a[i], b[j], acc[i][j], 0, 0, 0);
        __syncthreads();
    }

    #pragma unroll
    for (int i = 0; i < 4; ++i) {
        #pragma unroll
        for (int j = 0; j < 4; ++j) {
            #pragma unroll
            for (int e = 0; e < 4; ++e) {
                long row = m0 + wr * 64 + i * 16 + g * 4 + e;
                long col = n0 + wc * 64 + j * 16 + r;
                if (C_BF16) ((u16*)Cv)[row * N + col] = f2bf(acc[i][j][e]);
                else        ((float*)Cv)[row * N + col] = acc[i][j][e];
            }
        }
    }
}

// ---------------- Attention (unchanged from R1) ----------------
__global__ __launch_bounds__(256) void attn_kernel(const u16* __restrict__ Qb,
                                                   const u16* __restrict__ KVb,
                                                   const float* __restrict__ emb_h,
                                                   const float* __restrict__ emb_w,
                                                   u16* __restrict__ Ob) {
    __shared__ u16 Qs[64][32];
    __shared__ u16 Ks[NKEYS][32];
    __shared__ u16 Vs[NKEYS][32];
    __shared__ float eh[23][32];
    __shared__ float ew[23][32];
    __shared__ float relh[64][13];
    __shared__ float relw[64][13];
    __shared__ float sc[64][145];

    const int gblk = blockIdx.x;
    const int n = gblk & 7;
    const int bx = (gblk >> 3) & 15;
    const int by = (gblk >> 7) & 15;
    const int b = gblk >> 11;
    const int t = threadIdx.x;

    {
        int q = t >> 2, d0 = (t & 3) * 8;
        int qi = q >> 3, qj = q & 7;
        long row = ((long)b * 128 + by * 8 + qi) * 128 + bx * 8 + qj;
        *reinterpret_cast<uint4*>(&Qs[q][d0]) =
            *reinterpret_cast<const uint4*>(Qb + row * 256 + n * 32 + d0);
    }
    for (int u = t; u < NKEYS * 8; u += 256) {
        int kk = u >> 3, part = u & 7;
        int ky = kk / KVK, kx = kk % KVK;
        int gy = by * 8 + ky - 2, gx = bx * 8 + kx - 2;
        uint4 val = make_uint4(0u, 0u, 0u, 0u);
        if (gy >= 0 && gy < 128 && gx >= 0 && gx < 128) {
            long row = ((long)b * 128 + gy) * 128 + gx;
            val = *reinterpret_cast<const uint4*>(KVb + row * 512 + n * 64 + part * 8);
        }
        if (part < 4) *reinterpret_cast<uint4*>(&Ks[kk][part * 8]) = val;
        else         *reinterpret_cast<uint4*>(&Vs[kk][(part - 4) * 8]) = val;
    }
    for (int idx = t; idx < 736; idx += 256) {
        int d = idx / 23, r = idx % 23;
        eh[r][d] = emb_h[idx];
        ew[r][d] = emb_w[idx];
    }
    __syncthreads();

    #pragma unroll
    for (int u = t; u < 1536; u += 256) {
        int which = (u >= 768);
        int v = which ? u - 768 : u;
        int q = v / 12, kpos = v - 12 * (v / 12);
        int qi = q >> 3, qj = q & 7;
        int r = kpos - (which ? qj : qi) + 11;
        const float* e = which ? &ew[r][0] : &eh[r][0];
        float s = 0.f;
        #pragma unroll
        for (int d = 0; d < 32; ++d) s += bf2f(Qs[q][d]) * e[d];
        if (which) relw[q][kpos] = s;
        else       relh[q][kpos] = s;
    }
    __syncthreads();

    const int q = t >> 2, gg = t & 3;
    float qv[32];
    {
        const uint4* qp = reinterpret_cast<const uint4*>(&Qs[q][0]);
        #pragma unroll
        for (int c = 0; c < 4; ++c) {
            uint4 q4 = qp[c];
            qv[8 * c + 0] = bflo(q4.x); qv[8 * c + 1] = bfhi(q4.x);
            qv[8 * c + 2] = bflo(q4.y); qv[8 * c + 3] = bfhi(q4.y);
            qv[8 * c + 4] = bflo(q4.z); qv[8 * c + 5] = bfhi(q4.z);
            qv[8 * c + 6] = bflo(q4.w); qv[8 * c + 7] = bfhi(q4.w);
        }
    }
    const float scale = 0.17677669529663687f;
    float sreg[36];
    float mx = -1e30f;
    #pragma unroll
    for (int j = 0; j < 36; ++j) {
        int k = gg * 36 + j;
        float s = 0.f;
        const uint4* kp = reinterpret_cast<const uint4*>(&Ks[k][0]);
        #pragma unroll
        for (int c = 0; c < 4; ++c) {
            uint4 k4 = kp[c];
            s += bflo(k4.x) * qv[8 * c + 0]; s += bfhi(k4.x) * qv[8 * c + 1];
            s += bflo(k4.y) * qv[8 * c + 2]; s += bfhi(k4.y) * qv[8 * c + 3];
            s += bflo(k4.z) * qv[8 * c + 4]; s += bfhi(k4.z) * qv[8 * c + 5];
            s += bflo(k4.w) * qv[8 * c + 6]; s += bfhi(k4.w) * qv[8 * c + 7];
        }
        int ky = k / KVK, kx = k - KVK * ky;
        s = s * scale + relh[q][ky] + relw[q][kx];
        sreg[j] = s;
        mx = fmaxf(mx, s);
    }
    mx = fmaxf(mx, __shfl_xor(mx, 1));
    mx = fmaxf(mx, __shfl_xor(mx, 2));
    float sum = 0.f;
    #pragma unroll
    for (int j = 0; j < 36; ++j) {
        sreg[j] = __expf(sreg[j] - mx);
        sum += sreg[j];
    }
    sum += __shfl_xor(sum, 1);
    sum += __shfl_xor(sum, 2);
    const float inv = 1.0f / sum;
    #pragma unroll
    for (int j = 0; j < 36; ++j) sc[q][gg * 36 + j] = sreg[j] * inv;
    __syncthreads();

    float acc8[8] = {};
    const int d0 = gg * 8;
    for (int k = 0; k < NKEYS; ++k) {
        float p = sc[q][k];
        uint4 v4 = *reinterpret_cast<const uint4*>(&Vs[k][d0]);
        acc8[0] += p * bflo(v4.x); acc8[1] += p * bfhi(v4.x);
        acc8[2] += p * bflo(v4.y); acc8[3] += p * bfhi(v4.y);
        acc8[4] += p * bflo(v4.z); acc8[5] += p * bfhi(v4.z);
        acc8[6] += p * bflo(v4.w); acc8[7] += p * bfhi(v4.w);
    }
    {
        int qi = q >> 3, qj = q & 7;
        long row = ((long)b * 128 + by * 8 + qi) * 128 + bx * 8 + qj;
        ushort4 o0, o1;
        o0.x = f2bf(acc8[0]); o0.y = f2bf(acc8[1]); o0.z = f2bf(acc8[2]); o0.w = f2bf(acc8[3]);
        o1.x = f2bf(acc8[4]); o1.y = f2bf(acc8[5]); o1.z = f2bf(acc8[6]); o1.w = f2bf(acc8[7]);
        *reinterpret_cast<ushort4*>(Ob + row * 256 + n * 32 + d0) = o0;
        *reinterpret_cast<ushort4*>(Ob + row * 256 + n * 32 + d0 + 4) = o1;
    }
}

extern "C" void kernel_launch(void* const* d_in, const int* in_sizes, int n_in,
                              void* d_out, int out_size, void* d_ws, size_t ws_size,
                              hipStream_t stream) {
    const float* x     = (const float*)d_in[0];
    const float* w_q   = (const float*)d_in[1];
    const float* w_kv  = (const float*)d_in[2];
    const float* w_out = (const float*)d_in[3];
    const float* emb_h = (const float*)d_in[4];
    const float* emb_w = (const float*)d_in[5];

    // d_out (64MB f32 out): lower 32MB = xb bf16, upper 32MB = Qb bf16.
    // Both dead before the final gemm overwrites d_out with f32 results.
    u16* xb = (u16*)d_out;
    u16* Qb = (u16*)((char*)d_out + (size_t)33554432);
    char* ws = (char*)d_ws;
    u16* KVb   = (u16*)(ws);                     // 64MB
    u16* Ob    = (u16*)(ws + (size_t)67108864);  // 32MB
    u16* wqT   = (u16*)(ws + (size_t)100663296); // 128KB
    u16* wkvT  = (u16*)(ws + (size_t)100663296 + 131072);  // 256KB
    u16* woutT = (u16*)(ws + (size_t)100663296 + 393216);  // 128KB

    dim3 blk(256);
    conv_bf16<<<dim3(8192), blk, 0, stream>>>(x, xb);
    tr_bf16<<<dim3(256), blk, 0, stream>>>(w_q, wqT, 256);
    tr_bf16<<<dim3(512), blk, 0, stream>>>(w_kv, wkvT, 512);
    tr_bf16<<<dim3(256), blk, 0, stream>>>(w_out, woutT, 256);

    mfma_gemm<1><<<dim3(512, 2), blk, 0, stream>>>(xb, wqT, Qb, 256);
    mfma_gemm<1><<<dim3(512, 4), blk, 0, stream>>>(xb, wkvT, KVb, 512);
    attn_kernel<<<dim3(4 * 16 * 16 * 8), blk, 0, stream>>>(Qb, KVb, emb_h, emb_w, Ob);
    mfma_gemm<0><<<dim3(512, 2), blk, 0, stream>>>(Ob, woutT, (void*)d_out, 256);
}

// Round 3
// 242.606 us; speedup vs baseline: 4.6899x; 1.8983x over previous
//
#include <hip/hip_runtime.h>
#include <hip/hip_bf16.h>
#include <cstdint>

// HaloAttention: B=4, H=W=128, C=256, 8 heads, kd=32, block=8, halo=2, kvk=12.
// Pipeline: conv(x->bf16) + transpose(weights->bf16) ->
//   [mfma gemm Q][mfma gemm KV] -> [mfma attention] -> [mfma gemm out].

#define KVK 12
#define NKEYS 144

typedef unsigned int u32;
typedef unsigned short u16;
typedef __attribute__((ext_vector_type(8))) __bf16 bf16x8;
typedef __attribute__((ext_vector_type(4))) float f32x4;

__device__ __forceinline__ float bflo(u32 w) { return __uint_as_float(w << 16); }
__device__ __forceinline__ float bfhi(u32 w) { return __uint_as_float(w & 0xffff0000u); }
__device__ __forceinline__ float bf2f(u16 u) { return __uint_as_float(((u32)u) << 16); }
__device__ __forceinline__ u16 f2bf(float f) {
    u32 x = __float_as_uint(f);
    return (u16)((x + 0x7fffu + ((x >> 16) & 1u)) >> 16);
}
__device__ __forceinline__ u32 pack2(float lo, float hi) {
    return (u32)f2bf(lo) | ((u32)f2bf(hi) << 16);
}

__device__ __forceinline__ void gload16(const void* g, void* l) {
    __builtin_amdgcn_global_load_lds(
        (const __attribute__((address_space(1))) void*)g,
        (__attribute__((address_space(3))) void*)l, 16, 0, 0);
}

// ---------------- x (f32) -> bf16, 8 elems/thread ----------------
__global__ __launch_bounds__(256) void conv_bf16(const float* __restrict__ in,
                                                 u16* __restrict__ out) {
    int i = blockIdx.x * 256 + threadIdx.x;
    const float4* p = reinterpret_cast<const float4*>(in) + (long)i * 2;
    float4 a = p[0], b = p[1];
    uint4 o;
    o.x = pack2(a.x, a.y); o.y = pack2(a.z, a.w);
    o.z = pack2(b.x, b.y); o.w = pack2(b.z, b.w);
    reinterpret_cast<uint4*>(out)[i] = o;
}

// ---------------- W[256 x N] f32 -> WT[N x 256] bf16 ----------------
__global__ __launch_bounds__(256) void tr_bf16(const float* __restrict__ w,
                                               u16* __restrict__ wt, int N) {
    int idx = blockIdx.x * 256 + threadIdx.x;  // idx = n*256 + k
    int n = idx >> 8, k = idx & 255;
    wt[idx] = f2bf(w[(long)k * N + n]);
}

// ---------------- MFMA GEMM: C[M x N] = A[M x 256] * BT[N x 256]^T ----------
template <int C_BF16>
__global__ __launch_bounds__(256) void mfma_gemm(const u16* __restrict__ A,
                                                 const u16* __restrict__ BT,
                                                 void* __restrict__ Cv, int N) {
    __shared__ u16 As[4096];
    __shared__ u16 Bs[4096];
    const int t = threadIdx.x;
    const int w = t >> 6, lane = t & 63;
    const long m0 = (long)blockIdx.x * 128;
    const long n0 = (long)blockIdx.y * 128;
    const int wr = w >> 1, wc = w & 1;
    const int r = lane & 15, g = lane >> 4;

    f32x4 acc[4][4];
    #pragma unroll
    for (int i = 0; i < 4; ++i)
        #pragma unroll
        for (int j = 0; j < 4; ++j) acc[i][j] = (f32x4){0.f, 0.f, 0.f, 0.f};

    const int u0 = w * 128 + lane;
    const int row0 = u0 >> 2, cs0 = (u0 & 3) * 8;
    const int u1 = u0 + 64;
    const int row1 = u1 >> 2, cs1 = (u1 & 3) * 8;
    const u16* Ag0 = A + (m0 + row0) * 256 + cs0;
    const u16* Ag1 = A + (m0 + row1) * 256 + cs1;
    const u16* Bg0 = BT + (n0 + row0) * 256 + cs0;
    const u16* Bg1 = BT + (n0 + row1) * 256 + cs1;
    u16* AsW = &As[w * 1024];
    u16* BsW = &Bs[w * 1024];

    for (int k0 = 0; k0 < 256; k0 += 32) {
        gload16(Ag0 + k0, AsW);
        gload16(Ag1 + k0, AsW + 512);
        gload16(Bg0 + k0, BsW);
        gload16(Bg1 + k0, BsW + 512);
        __syncthreads();
        bf16x8 a[4], b[4];
        #pragma unroll
        for (int i = 0; i < 4; ++i)
            a[i] = *reinterpret_cast<const bf16x8*>(&As[(wr * 64 + i * 16 + r) * 32 + g * 8]);
        #pragma unroll
        for (int j = 0; j < 4; ++j)
            b[j] = *reinterpret_cast<const bf16x8*>(&Bs[(wc * 64 + j * 16 + r) * 32 + g * 8]);
        #pragma unroll
        for (int i = 0; i < 4; ++i)
            #pragma unroll
            for (int j = 0; j < 4; ++j)
                acc[i][j] = __builtin_amdgcn_mfma_f32_16x16x32_bf16(a[i], b[j], acc[i][j], 0, 0, 0);
        __syncthreads();
    }

    #pragma unroll
    for (int i = 0; i < 4; ++i) {
        #pragma unroll
        for (int j = 0; j < 4; ++j) {
            #pragma unroll
            for (int e = 0; e < 4; ++e) {
                long row = m0 + wr * 64 + i * 16 + g * 4 + e;
                long col = n0 + wc * 64 + j * 16 + r;
                if (C_BF16) ((u16*)Cv)[row * N + col] = f2bf(acc[i][j][e]);
                else        ((float*)Cv)[row * N + col] = acc[i][j][e];
            }
        }
    }
}

// ---------------- MFMA Attention ----------------
// grid = 8192 = (b, by, bx, head); 256 threads = 4 waves; wave w owns q-rows
// w*16..w*16+15. QK^T: 9 mfma_16x16x32 (kd=32 = one K-step). Softmax in regs
// on C-layout (row=g*4+e, col=r), shfl_xor over 16-lane r-group. P -> LDS bf16
// -> A-frags for PV (2 d-tiles x 5 k-slices, K padded 144->160 with zeros).
#define QS_S 40
#define KS_S 40
#define VT_S 168
#define P_S  168
#define EH_S 33

__global__ __launch_bounds__(256) void attn_mfma(const u16* __restrict__ Qb,
                                                 const u16* __restrict__ KVb,
                                                 const float* __restrict__ emb_h,
                                                 const float* __restrict__ emb_w,
                                                 u16* __restrict__ Ob) {
    __shared__ u16 Qs[64 * QS_S];
    __shared__ u16 Ks[NKEYS * KS_S];
    __shared__ u16 Vt[32 * VT_S];     // V transposed: Vt[d][k], cols 144..159 zero
    __shared__ float eh[23 * EH_S];
    __shared__ float ew[23 * EH_S];
    __shared__ float relh[64 * 13];
    __shared__ float relw[64 * 13];
    __shared__ u16 P[64 * P_S];       // cols 144..159 zero

    const int gblk = blockIdx.x;
    const int n = gblk & 7;
    const int bx = (gblk >> 3) & 15;
    const int by = (gblk >> 7) & 15;
    const int b = gblk >> 11;
    const int t = threadIdx.x;
    const int w = t >> 6, lane = t & 63;
    const int g = lane >> 4, r = lane & 15;

    // ---- load Q tile 64x32 ----
    {
        int q = t >> 2, d0 = (t & 3) * 8;
        int qi = q >> 3, qj = q & 7;
        long row = ((long)b * 128 + by * 8 + qi) * 128 + bx * 8 + qj;
        *reinterpret_cast<uint4*>(&Qs[q * QS_S + d0]) =
            *reinterpret_cast<const uint4*>(Qb + row * 256 + n * 32 + d0);
    }
    // ---- load K rows / scatter V transposed ----
    for (int u = t; u < NKEYS * 8; u += 256) {
        int kk = u >> 3, part = u & 7;
        int ky = kk / KVK, kx = kk - ky * KVK;
        int gy = by * 8 + ky - 2, gx = bx * 8 + kx - 2;
        uint4 val = make_uint4(0u, 0u, 0u, 0u);
        if ((unsigned)gy < 128u && (unsigned)gx < 128u) {
            long row = ((long)b * 128 + gy) * 128 + gx;
            val = *reinterpret_cast<const uint4*>(KVb + row * 512 + n * 64 + part * 8);
        }
        if (part < 4) {
            *reinterpret_cast<uint4*>(&Ks[kk * KS_S + part * 8]) = val;
        } else {
            int d0 = (part - 4) * 8;
            u16 tmp[8];
            *reinterpret_cast<uint4*>(tmp) = val;
            #pragma unroll
            for (int i = 0; i < 8; ++i) Vt[(d0 + i) * VT_S + kk] = tmp[i];
        }
    }
    // ---- embeddings (transposed, padded stride 33) ----
    for (int idx = t; idx < 736; idx += 256) {
        int d = idx / 23, rr = idx - 23 * (idx / 23);
        eh[rr * EH_S + d] = emb_h[idx];
        ew[rr * EH_S + d] = emb_w[idx];
    }
    // ---- zero pad columns 144..159 of P and Vt ----
    {
        uint4 z = make_uint4(0u, 0u, 0u, 0u);
        if (t < 64) {
            *reinterpret_cast<uint4*>(&P[t * P_S + 144]) = z;
            *reinterpret_cast<uint4*>(&P[t * P_S + 152]) = z;
        } else if (t < 96) {
            int d = t - 64;
            *reinterpret_cast<uint4*>(&Vt[d * VT_S + 144]) = z;
            *reinterpret_cast<uint4*>(&Vt[d * VT_S + 152]) = z;
        }
    }
    __syncthreads();

    // ---- relative logits: relh[q][p] = Q[q].emb_h[:, p-qi+11], relw likewise ----
    {
        int q = t >> 2, sub = t & 3;
        int qi = q >> 3, qj = q & 7;
        float qv[32];
        const uint4* qp = reinterpret_cast<const uint4*>(&Qs[q * QS_S]);
        #pragma unroll
        for (int c = 0; c < 4; ++c) {
            uint4 q4 = qp[c];
            qv[8 * c + 0] = bflo(q4.x); qv[8 * c + 1] = bfhi(q4.x);
            qv[8 * c + 2] = bflo(q4.y); qv[8 * c + 3] = bfhi(q4.y);
            qv[8 * c + 4] = bflo(q4.z); qv[8 * c + 5] = bfhi(q4.z);
            qv[8 * c + 6] = bflo(q4.w); qv[8 * c + 7] = bfhi(q4.w);
        }
        #pragma unroll
        for (int m = 0; m < 6; ++m) {
            int idx = sub * 6 + m;
            int which = idx >= 12;
            int kpos = idx - (which ? 12 : 0);
            int rr = kpos - (which ? qj : qi) + 11;
            const float* e = (which ? ew : eh) + rr * EH_S;
            float s = 0.f;
            #pragma unroll
            for (int d = 0; d < 32; ++d) s += qv[d] * e[d];
            if (which) relw[q * 13 + kpos] = s;
            else       relh[q * 13 + kpos] = s;
        }
    }
    __syncthreads();

    // ---- QK^T via MFMA: wave w = q-tile, j = key tile 0..8 ----
    bf16x8 qa = *reinterpret_cast<const bf16x8*>(&Qs[(w * 16 + r) * QS_S + g * 8]);
    f32x4 acc[9];
    #pragma unroll
    for (int j = 0; j < 9; ++j) {
        bf16x8 kb = *reinterpret_cast<const bf16x8*>(&Ks[(j * 16 + r) * KS_S + g * 8]);
        acc[j] = __builtin_amdgcn_mfma_f32_16x16x32_bf16(qa, kb, (f32x4){0.f, 0.f, 0.f, 0.f}, 0, 0, 0);
    }
    // ---- + scale + rel logits ----
    const float scale = 0.17677669529663687f;  // 1/sqrt(32)
    float sv[9][4];
    #pragma unroll
    for (int j = 0; j < 9; ++j) {
        int k = j * 16 + r;
        int ky = k / KVK, kx = k - ky * KVK;
        #pragma unroll
        for (int e = 0; e < 4; ++e) {
            int q = w * 16 + g * 4 + e;
            sv[j][e] = acc[j][e] * scale + relh[q * 13 + ky] + relw[q * 13 + kx];
        }
    }
    // ---- softmax across k (9 regs x 16 lanes), per e ----
    float inv[4];
    #pragma unroll
    for (int e = 0; e < 4; ++e) {
        float m = sv[0][e];
        #pragma unroll
        for (int j = 1; j < 9; ++j) m = fmaxf(m, sv[j][e]);
        m = fmaxf(m, __shfl_xor(m, 1));
        m = fmaxf(m, __shfl_xor(m, 2));
        m = fmaxf(m, __shfl_xor(m, 4));
        m = fmaxf(m, __shfl_xor(m, 8));
        float sum = 0.f;
        #pragma unroll
        for (int j = 0; j < 9; ++j) {
            sv[j][e] = __expf(sv[j][e] - m);
            sum += sv[j][e];
        }
        sum += __shfl_xor(sum, 1);
        sum += __shfl_xor(sum, 2);
        sum += __shfl_xor(sum, 4);
        sum += __shfl_xor(sum, 8);
        inv[e] = 1.0f / sum;
    }
    // ---- write P (bf16) for A-fragment reads ----
    #pragma unroll
    for (int j = 0; j < 9; ++j)
        #pragma unroll
        for (int e = 0; e < 4; ++e)
            P[(w * 16 + g * 4 + e) * P_S + j * 16 + r] = f2bf(sv[j][e] * inv[e]);
    __syncthreads();

    // ---- PV via MFMA: out tile 16x32 per wave, K 160 in 5 slices ----
    f32x4 o0 = (f32x4){0.f, 0.f, 0.f, 0.f};
    f32x4 o1 = (f32x4){0.f, 0.f, 0.f, 0.f};
    #pragma unroll
    for (int kk = 0; kk < 5; ++kk) {
        bf16x8 pa = *reinterpret_cast<const bf16x8*>(&P[(w * 16 + r) * P_S + kk * 32 + g * 8]);
        bf16x8 v0 = *reinterpret_cast<const bf16x8*>(&Vt[r * VT_S + kk * 32 + g * 8]);
        bf16x8 v1 = *reinterpret_cast<const bf16x8*>(&Vt[(16 + r) * VT_S + kk * 32 + g * 8]);
        o0 = __builtin_amdgcn_mfma_f32_16x16x32_bf16(pa, v0, o0, 0, 0, 0);
        o1 = __builtin_amdgcn_mfma_f32_16x16x32_bf16(pa, v1, o1, 0, 0, 0);
    }
    // ---- write out ----
    #pragma unroll
    for (int e = 0; e < 4; ++e) {
        int q = w * 16 + g * 4 + e;
        int qi = q >> 3, qj = q & 7;
        long row = ((long)b * 128 + by * 8 + qi) * 128 + bx * 8 + qj;
        Ob[row * 256 + n * 32 + r] = f2bf(o0[e]);
        Ob[row * 256 + n * 32 + 16 + r] = f2bf(o1[e]);
    }
}

extern "C" void kernel_launch(void* const* d_in, const int* in_sizes, int n_in,
                              void* d_out, int out_size, void* d_ws, size_t ws_size,
                              hipStream_t stream) {
    const float* x     = (const float*)d_in[0];
    const float* w_q   = (const float*)d_in[1];
    const float* w_kv  = (const float*)d_in[2];
    const float* w_out = (const float*)d_in[3];
    const float* emb_h = (const float*)d_in[4];
    const float* emb_w = (const float*)d_in[5];

    u16* xb = (u16*)d_out;
    u16* Qb = (u16*)((char*)d_out + (size_t)33554432);
    char* ws = (char*)d_ws;
    u16* KVb   = (u16*)(ws);                     // 64MB
    u16* Ob    = (u16*)(ws + (size_t)67108864);  // 32MB
    u16* wqT   = (u16*)(ws + (size_t)100663296);
    u16* wkvT  = (u16*)(ws + (size_t)100663296 + 131072);
    u16* woutT = (u16*)(ws + (size_t)100663296 + 393216);

    dim3 blk(256);
    conv_bf16<<<dim3(8192), blk, 0, stream>>>(x, xb);
    tr_bf16<<<dim3(256), blk, 0, stream>>>(w_q, wqT, 256);
    tr_bf16<<<dim3(512), blk, 0, stream>>>(w_kv, wkvT, 512);
    tr_bf16<<<dim3(256), blk, 0, stream>>>(w_out, woutT, 256);

    mfma_gemm<1><<<dim3(512, 2), blk, 0, stream>>>(xb, wqT, Qb, 256);
    mfma_gemm<1><<<dim3(512, 4), blk, 0, stream>>>(xb, wkvT, KVb, 512);
    attn_mfma<<<dim3(8192), blk, 0, stream>>>(Qb, KVb, emb_h, emb_w, Ob);
    mfma_gemm<0><<<dim3(512, 2), blk, 0, stream>>>(Ob, woutT, (void*)d_out, 256);
}

// Round 4
// 184.131 us; speedup vs baseline: 6.1792x; 1.3176x over previous
//
#include <hip/hip_runtime.h>
#include <hip/hip_bf16.h>
#include <cstdint>

// HaloAttention: B=4, H=W=128, C=256, 8 heads, kd=32, block=8, halo=2, kvk=12.
// conv(x->bf16) + prep_weights -> [mfma gemm Q][mfma gemm KV] -> [mfma attn] -> [mfma gemm out]

#define KVK 12
#define NKEYS 144

typedef unsigned int u32;
typedef unsigned short u16;
typedef __attribute__((ext_vector_type(8))) __bf16 bf16x8;
typedef __attribute__((ext_vector_type(4))) float f32x4;

__device__ __forceinline__ float bflo(u32 w) { return __uint_as_float(w << 16); }
__device__ __forceinline__ float bfhi(u32 w) { return __uint_as_float(w & 0xffff0000u); }
__device__ __forceinline__ float bf2f(u16 u) { return __uint_as_float(((u32)u) << 16); }
__device__ __forceinline__ u16 f2bf(float f) {
    u32 x = __float_as_uint(f);
    return (u16)((x + 0x7fffu + ((x >> 16) & 1u)) >> 16);
}
__device__ __forceinline__ u32 pack2(float lo, float hi) {
    return (u32)f2bf(lo) | ((u32)f2bf(hi) << 16);
}

__device__ __forceinline__ void gload16(const void* g, void* l) {
    __builtin_amdgcn_global_load_lds(
        (const __attribute__((address_space(1))) void*)g,
        (__attribute__((address_space(3))) void*)l, 16, 0, 0);
}

// ---------------- x (f32) -> bf16 ----------------
__global__ __launch_bounds__(256) void conv_bf16(const float* __restrict__ in,
                                                 u16* __restrict__ out) {
    int i = blockIdx.x * 256 + threadIdx.x;
    const float4* p = reinterpret_cast<const float4*>(in) + (long)i * 2;
    float4 a = p[0], b = p[1];
    uint4 o;
    o.x = pack2(a.x, a.y); o.y = pack2(a.z, a.w);
    o.z = pack2(b.x, b.y); o.w = pack2(b.z, b.w);
    reinterpret_cast<uint4*>(out)[i] = o;
}

// ---------------- all three weights: W[256 x N] f32 -> WT[N x 256] bf16 ------
__global__ __launch_bounds__(256) void prep_weights(const float* __restrict__ wq,
                                                    const float* __restrict__ wkv,
                                                    const float* __restrict__ wout,
                                                    u16* __restrict__ wqT,
                                                    u16* __restrict__ wkvT,
                                                    u16* __restrict__ woutT) {
    int blk = blockIdx.x;
    const float* src; u16* dst; int N; int base;
    if (blk < 256)      { src = wq;   dst = wqT;   N = 256; base = blk; }
    else if (blk < 768) { src = wkv;  dst = wkvT;  N = 512; base = blk - 256; }
    else                { src = wout; dst = woutT; N = 256; base = blk - 768; }
    int idx = base * 256 + threadIdx.x;
    int n = idx >> 8, k = idx & 255;
    dst[idx] = f2bf(src[(long)k * N + n]);
}

// ---------------- MFMA GEMM: C[M x N] = A[M x 256] * BT[N x 256]^T ----------
template <int C_BF16>
__global__ __launch_bounds__(256) void mfma_gemm(const u16* __restrict__ A,
                                                 const u16* __restrict__ BT,
                                                 void* __restrict__ Cv, int N) {
    __shared__ u16 As[4096];
    __shared__ u16 Bs[4096];
    const int t = threadIdx.x;
    const int w = t >> 6, lane = t & 63;
    const long m0 = (long)blockIdx.x * 128;
    const long n0 = (long)blockIdx.y * 128;
    const int wr = w >> 1, wc = w & 1;
    const int r = lane & 15, g = lane >> 4;

    f32x4 acc[4][4];
    #pragma unroll
    for (int i = 0; i < 4; ++i)
        #pragma unroll
        for (int j = 0; j < 4; ++j) acc[i][j] = (f32x4){0.f, 0.f, 0.f, 0.f};

    const int u0 = w * 128 + lane;
    const int row0 = u0 >> 2, cs0 = (u0 & 3) * 8;
    const int u1 = u0 + 64;
    const int row1 = u1 >> 2, cs1 = (u1 & 3) * 8;
    const u16* Ag0 = A + (m0 + row0) * 256 + cs0;
    const u16* Ag1 = A + (m0 + row1) * 256 + cs1;
    const u16* Bg0 = BT + (n0 + row0) * 256 + cs0;
    const u16* Bg1 = BT + (n0 + row1) * 256 + cs1;
    u16* AsW = &As[w * 1024];
    u16* BsW = &Bs[w * 1024];

    for (int k0 = 0; k0 < 256; k0 += 32) {
        gload16(Ag0 + k0, AsW);
        gload16(Ag1 + k0, AsW + 512);
        gload16(Bg0 + k0, BsW);
        gload16(Bg1 + k0, BsW + 512);
        __syncthreads();
        bf16x8 a[4], b[4];
        #pragma unroll
        for (int i = 0; i < 4; ++i)
            a[i] = *reinterpret_cast<const bf16x8*>(&As[(wr * 64 + i * 16 + r) * 32 + g * 8]);
        #pragma unroll
        for (int j = 0; j < 4; ++j)
            b[j] = *reinterpret_cast<const bf16x8*>(&Bs[(wc * 64 + j * 16 + r) * 32 + g * 8]);
        #pragma unroll
        for (int i = 0; i < 4; ++i)
            #pragma unroll
            for (int j = 0; j < 4; ++j)
                acc[i][j] = __builtin_amdgcn_mfma_f32_16x16x32_bf16(a[i], b[j], acc[i][j], 0, 0, 0);
        __syncthreads();
    }

    #pragma unroll
    for (int i = 0; i < 4; ++i) {
        #pragma unroll
        for (int j = 0; j < 4; ++j) {
            #pragma unroll
            for (int e = 0; e < 4; ++e) {
                long row = m0 + wr * 64 + i * 16 + g * 4 + e;
                long col = n0 + wc * 64 + j * 16 + r;
                if (C_BF16) ((u16*)Cv)[row * N + col] = f2bf(acc[i][j][e]);
                else        ((float*)Cv)[row * N + col] = acc[i][j][e];
            }
        }
    }
}

// ---------------- MFMA Attention ----------------
// 4 waves; wave w owns q-rows w*16..w*16+15. Rel logits via MFMA:
// RELHT[p][q] = sum_d ehT[p][d] Q[q][d]  (B-frag == QK^T's qa).
// relh read as RELHT[ky-qi+11][q] (float4 over e); relw scatter-stored to
// relwF[q][kx] (kx = p + qj - 11). P overlays {ehT,ewT,relhT,relwF}.
#define QS_S 40
#define KS_S 40
#define VT_S 168
#define P_S  168
#define RH_S 68

__global__ __launch_bounds__(256, 3) void attn_mfma(const u16* __restrict__ Qb,
                                                    const u16* __restrict__ KVb,
                                                    const float* __restrict__ emb_h,
                                                    const float* __restrict__ emb_w,
                                                    u16* __restrict__ Ob) {
    __shared__ u16 Qs[64 * QS_S];
    __shared__ u16 Ks[NKEYS * KS_S];
    __shared__ u16 Vt[32 * VT_S];                 // V^T: Vt[d][k], cols 144..159 zero
    __shared__ __align__(16) char blob[21504];    // max(13680 rel-phase, 21504 P)
    u16* ehT = (u16*)blob;                        // [32][32] bf16 (rows 0..22 valid)
    u16* ewT = (u16*)(blob + 2048);               // [32][32]
    float* relhT = (float*)(blob + 4096);         // [23][RH_S]
    float* relwF = (float*)(blob + 4096 + 23 * RH_S * 4);  // [64][13]
    u16* P = (u16*)blob;                          // [64][P_S], overlays after barrier

    const int gblk = blockIdx.x;
    const int n = gblk & 7;
    const int bx = (gblk >> 3) & 15;
    const int by = (gblk >> 7) & 15;
    const int b = gblk >> 11;
    const int t = threadIdx.x;
    const int w = t >> 6, lane = t & 63;
    const int g = lane >> 4, r = lane & 15;

    // ---- load Q tile 64x32 ----
    {
        int q = t >> 2, d0 = (t & 3) * 8;
        int qi = q >> 3, qj = q & 7;
        long row = ((long)b * 128 + by * 8 + qi) * 128 + bx * 8 + qj;
        *reinterpret_cast<uint4*>(&Qs[q * QS_S + d0]) =
            *reinterpret_cast<const uint4*>(Qb + row * 256 + n * 32 + d0);
    }
    // ---- load K rows / scatter V transposed ----
    for (int u = t; u < NKEYS * 8; u += 256) {
        int kk = u >> 3, part = u & 7;
        int ky = kk / KVK, kx = kk - ky * KVK;
        int gy = by * 8 + ky - 2, gx = bx * 8 + kx - 2;
        uint4 val = make_uint4(0u, 0u, 0u, 0u);
        if ((unsigned)gy < 128u && (unsigned)gx < 128u) {
            long row = ((long)b * 128 + gy) * 128 + gx;
            val = *reinterpret_cast<const uint4*>(KVb + row * 512 + n * 64 + part * 8);
        }
        if (part < 4) {
            *reinterpret_cast<uint4*>(&Ks[kk * KS_S + part * 8]) = val;
        } else {
            int d0 = (part - 4) * 8;
            u16 tmp[8];
            *reinterpret_cast<uint4*>(tmp) = val;
            #pragma unroll
            for (int i = 0; i < 8; ++i) Vt[(d0 + i) * VT_S + kk] = tmp[i];
        }
    }
    // ---- embeddings transposed to bf16: ehT[p][d] = emb_h[d*23+p] ----
    for (int idx = t; idx < 736; idx += 256) {
        int d = idx / 23, p = idx - 23 * (idx / 23);
        ehT[p * 32 + d] = f2bf(emb_h[idx]);
        ewT[p * 32 + d] = f2bf(emb_w[idx]);
    }
    // ---- zero Vt pad cols 144..159 ----
    if (t >= 224) {
        int d = t - 224;
        *reinterpret_cast<uint4*>(&Vt[d * VT_S + 144]) = make_uint4(0u, 0u, 0u, 0u);
        *reinterpret_cast<uint4*>(&Vt[d * VT_S + 152]) = make_uint4(0u, 0u, 0u, 0u);
    }
    __syncthreads();

    // ---- rel logits via MFMA (4 mfma/wave); write relhT + scatter relwF ----
    bf16x8 qa = *reinterpret_cast<const bf16x8*>(&Qs[(w * 16 + r) * QS_S + g * 8]);
    {
        bf16x8 ah0 = *reinterpret_cast<const bf16x8*>(&ehT[r * 32 + g * 8]);
        bf16x8 ah1 = *reinterpret_cast<const bf16x8*>(&ehT[(16 + r) * 32 + g * 8]);
        bf16x8 aw0 = *reinterpret_cast<const bf16x8*>(&ewT[r * 32 + g * 8]);
        bf16x8 aw1 = *reinterpret_cast<const bf16x8*>(&ewT[(16 + r) * 32 + g * 8]);
        f32x4 z = (f32x4){0.f, 0.f, 0.f, 0.f};
        f32x4 rh0 = __builtin_amdgcn_mfma_f32_16x16x32_bf16(ah0, qa, z, 0, 0, 0);
        f32x4 rh1 = __builtin_amdgcn_mfma_f32_16x16x32_bf16(ah1, qa, z, 0, 0, 0);
        f32x4 rw0 = __builtin_amdgcn_mfma_f32_16x16x32_bf16(aw0, qa, z, 0, 0, 0);
        f32x4 rw1 = __builtin_amdgcn_mfma_f32_16x16x32_bf16(aw1, qa, z, 0, 0, 0);
        const int q = w * 16 + r;       // output col
        const int qj = r & 7;
        #pragma unroll
        for (int ti = 0; ti < 2; ++ti) {
            #pragma unroll
            for (int e = 0; e < 4; ++e) {
                int p = ti * 16 + g * 4 + e;
                float vh = ti ? rh1[e] : rh0[e];
                float vw = ti ? rw1[e] : rw0[e];
                if (p < 23) relhT[p * RH_S + q] = vh;
                int kx = p + qj - 11;
                if (kx >= 0 && kx < 12) relwF[q * 13 + kx] = vw;
            }
        }
    }
    __syncthreads();

    // ---- QK^T via MFMA + rel + softmax ----
    f32x4 acc[9];
    #pragma unroll
    for (int j = 0; j < 9; ++j) {
        bf16x8 kb = *reinterpret_cast<const bf16x8*>(&Ks[(j * 16 + r) * KS_S + g * 8]);
        acc[j] = __builtin_amdgcn_mfma_f32_16x16x32_bf16(qa, kb, (f32x4){0.f, 0.f, 0.f, 0.f}, 0, 0, 0);
    }
    const float scale = 0.17677669529663687f;  // 1/sqrt(32)
    const int q0 = w * 16 + g * 4;
    const int qi = q0 >> 3;                    // constant over e=0..3
    float sv[9][4];
    #pragma unroll
    for (int j = 0; j < 9; ++j) {
        int k = j * 16 + r;
        int ky = k / KVK, kx = k - ky * KVK;
        float4 rh4 = *reinterpret_cast<const float4*>(&relhT[(ky - qi + 11) * RH_S + q0]);
        float rw0 = relwF[(q0 + 0) * 13 + kx];
        float rw1 = relwF[(q0 + 1) * 13 + kx];
        float rw2 = relwF[(q0 + 2) * 13 + kx];
        float rw3 = relwF[(q0 + 3) * 13 + kx];
        sv[j][0] = acc[j][0] * scale + rh4.x + rw0;
        sv[j][1] = acc[j][1] * scale + rh4.y + rw1;
        sv[j][2] = acc[j][2] * scale + rh4.z + rw2;
        sv[j][3] = acc[j][3] * scale + rh4.w + rw3;
    }
    float inv[4];
    #pragma unroll
    for (int e = 0; e < 4; ++e) {
        float m = sv[0][e];
        #pragma unroll
        for (int j = 1; j < 9; ++j) m = fmaxf(m, sv[j][e]);
        m = fmaxf(m, __shfl_xor(m, 1));
        m = fmaxf(m, __shfl_xor(m, 2));
        m = fmaxf(m, __shfl_xor(m, 4));
        m = fmaxf(m, __shfl_xor(m, 8));
        float sum = 0.f;
        #pragma unroll
        for (int j = 0; j < 9; ++j) {
            sv[j][e] = __expf(sv[j][e] - m);
            sum += sv[j][e];
        }
        sum += __shfl_xor(sum, 1);
        sum += __shfl_xor(sum, 2);
        sum += __shfl_xor(sum, 4);
        sum += __shfl_xor(sum, 8);
        inv[e] = 1.0f / sum;
    }
    __syncthreads();   // all rel reads done before P overlays blob

    // ---- write P (bf16) + zero pad cols ----
    #pragma unroll
    for (int j = 0; j < 9; ++j)
        #pragma unroll
        for (int e = 0; e < 4; ++e)
            P[(q0 + e) * P_S + j * 16 + r] = f2bf(sv[j][e] * inv[e]);
    if (t < 64) {
        *reinterpret_cast<uint4*>(&P[t * P_S + 144]) = make_uint4(0u, 0u, 0u, 0u);
        *reinterpret_cast<uint4*>(&P[t * P_S + 152]) = make_uint4(0u, 0u, 0u, 0u);
    }
    __syncthreads();

    // ---- PV via MFMA: out tile 16x32 per wave, K=160 in 5 slices ----
    f32x4 o0 = (f32x4){0.f, 0.f, 0.f, 0.f};
    f32x4 o1 = (f32x4){0.f, 0.f, 0.f, 0.f};
    #pragma unroll
    for (int kk = 0; kk < 5; ++kk) {
        bf16x8 pa = *reinterpret_cast<const bf16x8*>(&P[(w * 16 + r) * P_S + kk * 32 + g * 8]);
        bf16x8 v0 = *reinterpret_cast<const bf16x8*>(&Vt[r * VT_S + kk * 32 + g * 8]);
        bf16x8 v1 = *reinterpret_cast<const bf16x8*>(&Vt[(16 + r) * VT_S + kk * 32 + g * 8]);
        o0 = __builtin_amdgcn_mfma_f32_16x16x32_bf16(pa, v0, o0, 0, 0, 0);
        o1 = __builtin_amdgcn_mfma_f32_16x16x32_bf16(pa, v1, o1, 0, 0, 0);
    }
    #pragma unroll
    for (int e = 0; e < 4; ++e) {
        int q = q0 + e;
        int qi2 = q >> 3, qj2 = q & 7;
        long row = ((long)b * 128 + by * 8 + qi2) * 128 + bx * 8 + qj2;
        Ob[row * 256 + n * 32 + r] = f2bf(o0[e]);
        Ob[row * 256 + n * 32 + 16 + r] = f2bf(o1[e]);
    }
}

extern "C" void kernel_launch(void* const* d_in, const int* in_sizes, int n_in,
                              void* d_out, int out_size, void* d_ws, size_t ws_size,
                              hipStream_t stream) {
    const float* x     = (const float*)d_in[0];
    const float* w_q   = (const float*)d_in[1];
    const float* w_kv  = (const float*)d_in[2];
    const float* w_out = (const float*)d_in[3];
    const float* emb_h = (const float*)d_in[4];
    const float* emb_w = (const float*)d_in[5];

    u16* xb = (u16*)d_out;                              // 32MB (dead before final gemm)
    u16* Qb = (u16*)((char*)d_out + (size_t)33554432);  // 32MB (dead before final gemm)
    char* ws = (char*)d_ws;
    u16* KVb   = (u16*)(ws);                            // 64MB
    u16* Ob    = (u16*)(ws + (size_t)67108864);         // 32MB
    u16* wqT   = (u16*)(ws + (size_t)100663296);
    u16* wkvT  = (u16*)(ws + (size_t)100663296 + 131072);
    u16* woutT = (u16*)(ws + (size_t)100663296 + 393216);

    dim3 blk(256);
    conv_bf16<<<dim3(8192), blk, 0, stream>>>(x, xb);
    prep_weights<<<dim3(1024), blk, 0, stream>>>(w_q, w_kv, w_out, wqT, wkvT, woutT);
    mfma_gemm<1><<<dim3(512, 2), blk, 0, stream>>>(xb, wqT, Qb, 256);
    mfma_gemm<1><<<dim3(512, 4), blk, 0, stream>>>(xb, wkvT, KVb, 512);
    attn_mfma<<<dim3(8192), blk, 0, stream>>>(Qb, KVb, emb_h, emb_w, Ob);
    mfma_gemm<0><<<dim3(512, 2), blk, 0, stream>>>(Ob, woutT, (void*)d_out, 256);
}

// Round 5
// 165.942 us; speedup vs baseline: 6.8566x; 1.1096x over previous
//
#include <hip/hip_runtime.h>
#include <hip/hip_bf16.h>
#include <cstdint>

// HaloAttention: B=4, H=W=128, C=256, 8 heads, kd=32, block=8, halo=2, kvk=12.
// conv(x->bf16) + prep_weights -> [gemm Q][gemm KV (K pre-scaled)] ->
// [attn: rel folded into augmented-K MFMA, swapped QK, reg-resident P] -> [gemm out]

#define KVK 12
#define NKEYS 144
#define VT_S 160

typedef unsigned int u32;
typedef unsigned short u16;
typedef __attribute__((ext_vector_type(8))) __bf16 bf16x8;
typedef __attribute__((ext_vector_type(4))) float f32x4;
typedef __attribute__((ext_vector_type(4))) u32 u32x4;

__device__ __forceinline__ u16 f2bf(float f) {
    u32 x = __float_as_uint(f);
    return (u16)((x + 0x7fffu + ((x >> 16) & 1u)) >> 16);
}
__device__ __forceinline__ u16 f2bfn(float f) {   // native RNE convert
    __bf16 h = (__bf16)f;
    return *reinterpret_cast<u16*>(&h);
}
__device__ __forceinline__ u32 pack2(float lo, float hi) {
    return (u32)f2bf(lo) | ((u32)f2bf(hi) << 16);
}
__device__ __forceinline__ u32 cvtpk(float lo, float hi) {
    u32 d;
    asm("v_cvt_pk_bf16_f32 %0, %1, %2" : "=v"(d) : "v"(lo), "v"(hi));
    return d;
}

__device__ __forceinline__ void gload16(const void* g, void* l) {
    __builtin_amdgcn_global_load_lds(
        (const __attribute__((address_space(1))) void*)g,
        (__attribute__((address_space(3))) void*)l, 16, 0, 0);
}

// ---------------- x (f32) -> bf16 ----------------
__global__ __launch_bounds__(256) void conv_bf16(const float* __restrict__ in,
                                                 u16* __restrict__ out) {
    int i = blockIdx.x * 256 + threadIdx.x;
    const float4* p = reinterpret_cast<const float4*>(in) + (long)i * 2;
    float4 a = p[0], b = p[1];
    uint4 o;
    o.x = pack2(a.x, a.y); o.y = pack2(a.z, a.w);
    o.z = pack2(b.x, b.y); o.w = pack2(b.z, b.w);
    reinterpret_cast<uint4*>(out)[i] = o;
}

// ---------------- weights: W[256 x N] f32 -> WT[N x 256] bf16 ----------------
__global__ __launch_bounds__(256) void prep_weights(const float* __restrict__ wq,
                                                    const float* __restrict__ wkv,
                                                    const float* __restrict__ wout,
                                                    u16* __restrict__ wqT,
                                                    u16* __restrict__ wkvT,
                                                    u16* __restrict__ woutT) {
    int blk = blockIdx.x;
    const float* src; u16* dst; int N; int base;
    if (blk < 256)      { src = wq;   dst = wqT;   N = 256; base = blk; }
    else if (blk < 768) { src = wkv;  dst = wkvT;  N = 512; base = blk - 256; }
    else                { src = wout; dst = woutT; N = 256; base = blk - 768; }
    int idx = base * 256 + threadIdx.x;
    int n = idx >> 8, k = idx & 255;
    dst[idx] = f2bf(src[(long)k * N + n]);
}

// ---------------- MFMA GEMM: C[M x N] = A[M x 256] * BT[N x 256]^T ----------
// SCALEK: multiply K-half columns ((col&32)==0) by 1/sqrt(32) in epilogue.
template <int C_BF16, int SCALEK>
__global__ __launch_bounds__(256) void mfma_gemm(const u16* __restrict__ A,
                                                 const u16* __restrict__ BT,
                                                 void* __restrict__ Cv, int N) {
    __shared__ u16 As[4096];
    __shared__ u16 Bs[4096];
    const int t = threadIdx.x;
    const int w = t >> 6, lane = t & 63;
    const long m0 = (long)blockIdx.x * 128;
    const long n0 = (long)blockIdx.y * 128;
    const int wr = w >> 1, wc = w & 1;
    const int r = lane & 15, g = lane >> 4;

    f32x4 acc[4][4];
    #pragma unroll
    for (int i = 0; i < 4; ++i)
        #pragma unroll
        for (int j = 0; j < 4; ++j) acc[i][j] = (f32x4){0.f, 0.f, 0.f, 0.f};

    const int u0 = w * 128 + lane;
    const int row0 = u0 >> 2, cs0 = (u0 & 3) * 8;
    const int u1 = u0 + 64;
    const int row1 = u1 >> 2, cs1 = (u1 & 3) * 8;
    const u16* Ag0 = A + (m0 + row0) * 256 + cs0;
    const u16* Ag1 = A + (m0 + row1) * 256 + cs1;
    const u16* Bg0 = BT + (n0 + row0) * 256 + cs0;
    const u16* Bg1 = BT + (n0 + row1) * 256 + cs1;
    u16* AsW = &As[w * 1024];
    u16* BsW = &Bs[w * 1024];

    for (int k0 = 0; k0 < 256; k0 += 32) {
        gload16(Ag0 + k0, AsW);
        gload16(Ag1 + k0, AsW + 512);
        gload16(Bg0 + k0, BsW);
        gload16(Bg1 + k0, BsW + 512);
        __syncthreads();
        bf16x8 a[4], b[4];
        #pragma unroll
        for (int i = 0; i < 4; ++i)
            a[i] = *reinterpret_cast<const bf16x8*>(&As[(wr * 64 + i * 16 + r) * 32 + g * 8]);
        #pragma unroll
        for (int j = 0; j < 4; ++j)
            b[j] = *reinterpret_cast<const bf16x8*>(&Bs[(wc * 64 + j * 16 + r) * 32 + g * 8]);
        #pragma unroll
        for (int i = 0; i < 4; ++i)
            #pragma unroll
            for (int j = 0; j < 4; ++j)
                acc[i][j] = __builtin_amdgcn_mfma_f32_16x16x32_bf16(a[i], b[j], acc[i][j], 0, 0, 0);
        __syncthreads();
    }

    #pragma unroll
    for (int i = 0; i < 4; ++i) {
        #pragma unroll
        for (int j = 0; j < 4; ++j) {
            long col = n0 + wc * 64 + j * 16 + r;
            float mult = (SCALEK && ((col & 32) == 0)) ? 0.17677669529663687f : 1.0f;
            #pragma unroll
            for (int e = 0; e < 4; ++e) {
                long row = m0 + wr * 64 + i * 16 + g * 4 + e;
                if (C_BF16) ((u16*)Cv)[row * N + col] = f2bfn(acc[i][j][e] * mult);
                else        ((float*)Cv)[row * N + col] = acc[i][j][e];
            }
        }
    }
}

// ---------------- MFMA Attention (augmented-K, swapped, reg-P) ----------------
// 4 waves; wave w owns queries q = w*16 + r (r = lane&15). K' = [scale*K | onehot(ky)
// | onehot(kx) | 0]; Q' = [Q | relh_q | relw_q | 0]. Swapped QK: acc[j][e] =
// S[k=16j+4g+e][q]. Softmax lane-local + 2 shuffles. P packed bf16 in regs,
// shfl-exchanged into PV B-fragments. PV: O^T[d][q] = Vt-frag x P-frag; inv applied
// at output. Barriers: 2.
__global__ __launch_bounds__(256, 4) void attn_mfma(const u16* __restrict__ Qb,
                                                    const u16* __restrict__ KVb,
                                                    const float* __restrict__ emb_h,
                                                    const float* __restrict__ emb_w,
                                                    u16* __restrict__ Ob) {
    __shared__ u16 Ks[NKEYS * 64];   // [k][64]: 0..31 scale*K, 32..43 onehot ky,
                                     // 44..55 onehot kx, 56..63 zero. XOR-swizzled.
    __shared__ u16 Vt[32 * VT_S];    // V^T [d][k], cols 144..159 zero, part-swizzled
    __shared__ u16 Qe[64 * 32];      // Q' ext dims: [q][ 0..11 relh | 12..23 relw | 0 ]
    __shared__ u16 ehT[1024];        // [32][32], rows 0..22 valid
    __shared__ u16 ewT[1024];

    const int gblk = blockIdx.x;
    const int n = gblk & 7;
    const int bx = (gblk >> 3) & 15;
    const int by = (gblk >> 7) & 15;
    const int b = gblk >> 11;
    const int t = threadIdx.x;
    const int w = t >> 6, lane = t & 63;
    const int g = lane >> 4, r = lane & 15;

    const int q = w * 16 + r;           // this lane's query
    const int qi = q >> 3, qj = q & 7;
    const long qrow = ((long)b * 128 + by * 8 + qi) * 128 + bx * 8 + qj;

    // ---- qa1: Q fragment direct from global (B-operand rows = q) ----
    bf16x8 qa1 = *reinterpret_cast<const bf16x8*>(Qb + qrow * 256 + n * 32 + g * 8);

    // ---- load K (swizzled rows) / scatter V transposed ----
    for (int u = t; u < NKEYS * 8; u += 256) {
        int kk = u >> 3, part = u & 7;
        int ky = kk / KVK, kx = kk - ky * KVK;
        int gy = by * 8 + ky - 2, gx = bx * 8 + kx - 2;
        uint4 val = make_uint4(0u, 0u, 0u, 0u);
        if ((unsigned)gy < 128u && (unsigned)gx < 128u) {
            long row = ((long)b * 128 + gy) * 128 + gx;
            val = *reinterpret_cast<const uint4*>(KVb + row * 512 + n * 64 + part * 8);
        }
        if (part < 4) {
            int col = (part * 8) ^ ((kk & 7) << 3);
            *reinterpret_cast<uint4*>(&Ks[kk * 64 + col]) = val;
        } else {
            int d0 = (part - 4) * 8;
            u16 tmp[8];
            *reinterpret_cast<uint4*>(tmp) = val;
            #pragma unroll
            for (int i = 0; i < 8; ++i) {
                int d = d0 + i;
                Vt[d * VT_S + (kk ^ (((d >> 3) & 3) << 3))] = tmp[i];
            }
        }
    }
    // ---- Ks ext cols 32..63 zero (one-hots written phase 1) ----
    for (int u = t; u < 576; u += 256) {
        int kk = u >> 2;
        int col = (32 + (u & 3) * 8) ^ ((kk & 7) << 3);
        *reinterpret_cast<uint4*>(&Ks[kk * 64 + col]) = make_uint4(0u, 0u, 0u, 0u);
    }
    // ---- Qe cols 24..31 zero ----
    if (t < 64) *reinterpret_cast<uint4*>(&Qe[t * 32 + 24]) = make_uint4(0u, 0u, 0u, 0u);
    // ---- Vt pad cols 144..159 zero ----
    if (t >= 224) {
        int d = t - 224;
        int sw = ((d >> 3) & 3) << 3;
        *reinterpret_cast<uint4*>(&Vt[d * VT_S + (144 ^ sw)]) = make_uint4(0u, 0u, 0u, 0u);
        *reinterpret_cast<uint4*>(&Vt[d * VT_S + (152 ^ sw)]) = make_uint4(0u, 0u, 0u, 0u);
    }
    // ---- embeddings transposed bf16: ehT[p][d] = emb_h[d*23+p] ----
    for (int idx = t; idx < 736; idx += 256) {
        int d = idx / 23, p = idx - 23 * (idx / 23);
        ehT[p * 32 + d] = f2bfn(emb_h[idx]);
        ewT[p * 32 + d] = f2bfn(emb_w[idx]);
    }
    __syncthreads();

    // ---- phase 1: rel-MFMA -> scatter rel values into Qe; one-hots into Ks ----
    {
        bf16x8 ah0 = *reinterpret_cast<const bf16x8*>(&ehT[r * 32 + g * 8]);
        bf16x8 ah1 = *reinterpret_cast<const bf16x8*>(&ehT[(16 + r) * 32 + g * 8]);
        bf16x8 aw0 = *reinterpret_cast<const bf16x8*>(&ewT[r * 32 + g * 8]);
        bf16x8 aw1 = *reinterpret_cast<const bf16x8*>(&ewT[(16 + r) * 32 + g * 8]);
        f32x4 z = (f32x4){0.f, 0.f, 0.f, 0.f};
        f32x4 rh0 = __builtin_amdgcn_mfma_f32_16x16x32_bf16(ah0, qa1, z, 0, 0, 0);
        f32x4 rh1 = __builtin_amdgcn_mfma_f32_16x16x32_bf16(ah1, qa1, z, 0, 0, 0);
        f32x4 rw0 = __builtin_amdgcn_mfma_f32_16x16x32_bf16(aw0, qa1, z, 0, 0, 0);
        f32x4 rw1 = __builtin_amdgcn_mfma_f32_16x16x32_bf16(aw1, qa1, z, 0, 0, 0);
        #pragma unroll
        for (int ti = 0; ti < 2; ++ti) {
            #pragma unroll
            for (int e = 0; e < 4; ++e) {
                int p = ti * 16 + g * 4 + e;
                float vh = ti ? rh1[e] : rh0[e];
                float vw = ti ? rw1[e] : rw0[e];
                int kyd = p + qi - 11;
                int kxd = p + qj - 11;
                if ((unsigned)kyd < 12u) Qe[q * 32 + kyd] = f2bfn(vh);
                if ((unsigned)kxd < 12u) Qe[q * 32 + 12 + kxd] = f2bfn(vw);
            }
        }
        if (t < NKEYS) {
            int ky = (t * 171) >> 11;
            int kx = t - 12 * ky;
            int sw = (t & 7) << 3;
            Ks[t * 64 + ((32 + ky) ^ sw)] = 0x3F80;  // bf16 1.0
            Ks[t * 64 + ((44 + kx) ^ sw)] = 0x3F80;
        }
    }
    __syncthreads();

    // ---- phase 2: augmented QK^T, swapped: acc[j][e] = S[16j+4g+e][q] ----
    bf16x8 qa2 = *reinterpret_cast<const bf16x8*>(&Qe[q * 32 + g * 8]);
    f32x4 acc[9];
    #pragma unroll
    for (int j = 0; j < 9; ++j) {
        int krow = j * 16 + r;
        int sw = (r & 7) << 3;
        bf16x8 kb0 = *reinterpret_cast<const bf16x8*>(&Ks[krow * 64 + ((g * 8) ^ sw)]);
        bf16x8 kb1 = *reinterpret_cast<const bf16x8*>(&Ks[krow * 64 + ((32 + g * 8) ^ sw)]);
        f32x4 z = (f32x4){0.f, 0.f, 0.f, 0.f};
        acc[j] = __builtin_amdgcn_mfma_f32_16x16x32_bf16(kb1, qa2,
                 __builtin_amdgcn_mfma_f32_16x16x32_bf16(kb0, qa1, z, 0, 0, 0), 0, 0, 0);
    }

    // ---- softmax (lane-local over 36 + shfl across g) ----
    float mx = -1e30f;
    #pragma unroll
    for (int j = 0; j < 9; ++j)
        #pragma unroll
        for (int e = 0; e < 4; ++e) mx = fmaxf(mx, acc[j][e]);
    mx = fmaxf(mx, __shfl_xor(mx, 16));
    mx = fmaxf(mx, __shfl_xor(mx, 32));
    float sum = 0.f;
    u32 pkA[9], pkB[9];
    #pragma unroll
    for (int j = 0; j < 9; ++j) {
        float e0 = __expf(acc[j][0] - mx);
        float e1 = __expf(acc[j][1] - mx);
        float e2 = __expf(acc[j][2] - mx);
        float e3 = __expf(acc[j][3] - mx);
        sum += (e0 + e1) + (e2 + e3);
        pkA[j] = cvtpk(e0, e1);
        pkB[j] = cvtpk(e2, e3);
    }
    sum += __shfl_xor(sum, 16);
    sum += __shfl_xor(sum, 32);
    const float inv = __builtin_amdgcn_rcpf(sum);

    // ---- PV: exchange P into B-frags, MFMA against Vt ----
    const int laneA = r + ((g & 1) << 5);
    const int laneB = laneA + 16;
    const bool hi = (g >> 1) != 0;
    const int sw0 = (r >> 3) << 3;          // Vt swizzle for rows r (d 0..15)
    const int sw1 = (2 + (r >> 3)) << 3;    // for rows 16+r
    f32x4 o0 = (f32x4){0.f, 0.f, 0.f, 0.f};
    f32x4 o1 = (f32x4){0.f, 0.f, 0.f, 0.f};
    #pragma unroll
    for (int kk = 0; kk < 5; ++kk) {
        u32 w0, w1, w2, w3;
        if (kk < 4) {
            int jA = 2 * kk, jB = 2 * kk + 1;
            u32 a0 = (u32)__shfl((int)pkA[jA], laneA);
            u32 a1 = (u32)__shfl((int)pkA[jB], laneA);
            u32 b0 = (u32)__shfl((int)pkB[jA], laneA);
            u32 b1 = (u32)__shfl((int)pkB[jB], laneA);
            u32 c0 = (u32)__shfl((int)pkA[jA], laneB);
            u32 c1 = (u32)__shfl((int)pkA[jB], laneB);
            u32 d0 = (u32)__shfl((int)pkB[jA], laneB);
            u32 d1 = (u32)__shfl((int)pkB[jB], laneB);
            w0 = hi ? a1 : a0; w1 = hi ? b1 : b0;
            w2 = hi ? c1 : c0; w3 = hi ? d1 : d0;
        } else {
            u32 a0 = (u32)__shfl((int)pkA[8], laneA);
            u32 b0 = (u32)__shfl((int)pkB[8], laneA);
            u32 c0 = (u32)__shfl((int)pkA[8], laneB);
            u32 d0 = (u32)__shfl((int)pkB[8], laneB);
            w0 = hi ? 0u : a0; w1 = hi ? 0u : b0;
            w2 = hi ? 0u : c0; w3 = hi ? 0u : d0;
        }
        u32x4 ww = (u32x4){w0, w1, w2, w3};
        bf16x8 pfrag = __builtin_bit_cast(bf16x8, ww);
        bf16x8 va0 = *reinterpret_cast<const bf16x8*>(&Vt[r * VT_S + ((kk * 32 + g * 8) ^ sw0)]);
        bf16x8 va1 = *reinterpret_cast<const bf16x8*>(&Vt[(16 + r) * VT_S + ((kk * 32 + g * 8) ^ sw1)]);
        o0 = __builtin_amdgcn_mfma_f32_16x16x32_bf16(va0, pfrag, o0, 0, 0, 0);
        o1 = __builtin_amdgcn_mfma_f32_16x16x32_bf16(va1, pfrag, o1, 0, 0, 0);
    }

    // ---- output: O^T[d][q], d = g*4+e (o0) and 16+g*4+e (o1); packed stores ----
    {
        uint2 s0, s1;
        s0.x = cvtpk(o0[0] * inv, o0[1] * inv);
        s0.y = cvtpk(o0[2] * inv, o0[3] * inv);
        s1.x = cvtpk(o1[0] * inv, o1[1] * inv);
        s1.y = cvtpk(o1[2] * inv, o1[3] * inv);
        *reinterpret_cast<uint2*>(Ob + qrow * 256 + n * 32 + g * 4) = s0;
        *reinterpret_cast<uint2*>(Ob + qrow * 256 + n * 32 + 16 + g * 4) = s1;
    }
}

extern "C" void kernel_launch(void* const* d_in, const int* in_sizes, int n_in,
                              void* d_out, int out_size, void* d_ws, size_t ws_size,
                              hipStream_t stream) {
    const float* x     = (const float*)d_in[0];
    const float* w_q   = (const float*)d_in[1];
    const float* w_kv  = (const float*)d_in[2];
    const float* w_out = (const float*)d_in[3];
    const float* emb_h = (const float*)d_in[4];
    const float* emb_w = (const float*)d_in[5];

    u16* xb = (u16*)d_out;                              // 32MB (dead before final gemm)
    u16* Qb = (u16*)((char*)d_out + (size_t)33554432);  // 32MB (dead before final gemm)
    char* ws = (char*)d_ws;
    u16* KVb   = (u16*)(ws);                            // 64MB
    u16* Ob    = (u16*)(ws + (size_t)67108864);         // 32MB
    u16* wqT   = (u16*)(ws + (size_t)100663296);
    u16* wkvT  = (u16*)(ws + (size_t)100663296 + 131072);
    u16* woutT = (u16*)(ws + (size_t)100663296 + 393216);

    dim3 blk(256);
    conv_bf16<<<dim3(8192), blk, 0, stream>>>(x, xb);
    prep_weights<<<dim3(1024), blk, 0, stream>>>(w_q, w_kv, w_out, wqT, wkvT, woutT);
    mfma_gemm<1, 0><<<dim3(512, 2), blk, 0, stream>>>(xb, wqT, Qb, 256);
    mfma_gemm<1, 1><<<dim3(512, 4), blk, 0, stream>>>(xb, wkvT, KVb, 512);
    attn_mfma<<<dim3(8192), blk, 0, stream>>>(Qb, KVb, emb_h, emb_w, Ob);
    mfma_gemm<0, 0><<<dim3(512, 2), blk, 0, stream>>>(Ob, woutT, (void*)d_out, 256);
}

// Round 7
// 160.850 us; speedup vs baseline: 7.0736x; 1.0317x over previous
//
#include <hip/hip_runtime.h>
#include <hip/hip_bf16.h>
#include <cstdint>

// HaloAttention: B=4, H=W=128, C=256, 8 heads, kd=32, block=8, halo=2, kvk=12.
// prep_weights (W^T bf16, K pre-scaled by log2e/sqrt(32), emb^T bf16) ->
// gemm_qkv (f32 x staged+converted in-kernel) -> attn (augmented-K, log2-domain
// softmax, LDS P^T) -> gemm out.

#define KVK 12
#define NKEYS 144
#define VT_S 160
#define PT_S 168
#define LOG2E 1.4426950408889634f

typedef unsigned int u32;
typedef unsigned short u16;
typedef __attribute__((ext_vector_type(8))) __bf16 bf16x8;
typedef __attribute__((ext_vector_type(4))) float f32x4;

__device__ __forceinline__ u16 f2bf(float f) {
    u32 x = __float_as_uint(f);
    return (u16)((x + 0x7fffu + ((x >> 16) & 1u)) >> 16);
}
__device__ __forceinline__ u32 cvtpk(float lo, float hi) {
    u32 d;
    asm("v_cvt_pk_bf16_f32 %0, %1, %2" : "=v"(d) : "v"(lo), "v"(hi));
    return d;
}
__device__ __forceinline__ float max3f(float a, float b, float c) {
    float d;
    asm("v_max3_f32 %0, %1, %2, %3" : "=v"(d) : "v"(a), "v"(b), "v"(c));
    return d;
}
__device__ __forceinline__ float exp2a(float x) {
    float d;
    asm("v_exp_f32 %0, %1" : "=v"(d) : "v"(x));
    return d;
}
__device__ __forceinline__ void gload16(const void* g, void* l) {
    __builtin_amdgcn_global_load_lds(
        (const __attribute__((address_space(1))) void*)g,
        (__attribute__((address_space(3))) void*)l, 16, 0, 0);
}

// ---------------- prep: W^T bf16 (K pre-scaled), emb^T bf16 ----------------
__global__ __launch_bounds__(256) void prep_weights(const float* __restrict__ wq,
                                                    const float* __restrict__ wkv,
                                                    const float* __restrict__ wout,
                                                    u16* __restrict__ wT,
                                                    u16* __restrict__ woutT,
                                                    const float* __restrict__ emb_h,
                                                    const float* __restrict__ emb_w,
                                                    u16* __restrict__ embT) {
    int blk = blockIdx.x, t = threadIdx.x;
    if (blk < 256) {
        int idx = blk * 256 + t; int nn = idx >> 8, k = idx & 255;
        wT[idx] = f2bf(wq[(long)k * 256 + nn]);
    } else if (blk < 768) {
        int idx = (blk - 256) * 256 + t; int nn = idx >> 8, k = idx & 255;
        float v = wkv[(long)k * 512 + nn];
        if ((nn & 32) == 0) v *= 0.2550348642f;  // (1/sqrt(32)) * log2(e)
        wT[65536 + idx] = f2bf(v);
    } else if (blk < 1024) {
        int idx = (blk - 768) * 256 + t; int nn = idx >> 8, k = idx & 255;
        woutT[idx] = f2bf(wout[(long)k * 256 + nn]);
    } else if (blk == 1024) {
        for (int i = t; i < 736; i += 256) {
            int p = i >> 5, d = i & 31;
            embT[i] = f2bf(emb_h[d * 23 + p]);
        }
    } else {
        for (int i = t; i < 736; i += 256) {
            int p = i >> 5, d = i & 31;
            embT[736 + i] = f2bf(emb_w[d * 23 + p]);
        }
    }
}

// ------------- fused QKV GEMM: [Q|KV] = x(f32) @ [wq|wkv], A converted in-kernel ---
__global__ __launch_bounds__(256) void gemm_qkv(const float* __restrict__ X,
                                                const u16* __restrict__ WT,
                                                u16* __restrict__ Qb,
                                                u16* __restrict__ KVb) {
    __shared__ u16 As[4096];
    __shared__ u16 Bs[4096];
    const int t = threadIdx.x;
    const int w = t >> 6, lane = t & 63;
    const long m0 = (long)blockIdx.x * 128;
    const long n0 = (long)blockIdx.y * 128;
    const int wr = w >> 1, wc = w & 1;
    const int r = lane & 15, g = lane >> 4;

    f32x4 acc[4][4];
    #pragma unroll
    for (int i = 0; i < 4; ++i)
        #pragma unroll
        for (int j = 0; j < 4; ++j) acc[i][j] = (f32x4){0.f, 0.f, 0.f, 0.f};

    // A staging (f32 -> bf16 in regs): thread handles rows t>>2 and t>>2+64
    const int rowA0 = t >> 2, csA = (t & 3) * 8;
    const int rowA1 = rowA0 + 64;
    const float* Xg0 = X + (m0 + rowA0) * 256 + csA;
    const float* Xg1 = X + (m0 + rowA1) * 256 + csA;
    // B staging via global_load_lds
    const int u0 = w * 128 + lane;
    const int rowB0 = u0 >> 2, csB0 = (u0 & 3) * 8;
    const int u1 = u0 + 64;
    const int rowB1 = u1 >> 2, csB1 = (u1 & 3) * 8;
    const u16* Bg0 = WT + (n0 + rowB0) * 256 + csB0;
    const u16* Bg1 = WT + (n0 + rowB1) * 256 + csB1;
    u16* BsW = &Bs[w * 1024];

    for (int k0 = 0; k0 < 256; k0 += 32) {
        float4 a0 = *reinterpret_cast<const float4*>(Xg0 + k0);
        float4 a1 = *reinterpret_cast<const float4*>(Xg0 + k0 + 4);
        float4 c0 = *reinterpret_cast<const float4*>(Xg1 + k0);
        float4 c1 = *reinterpret_cast<const float4*>(Xg1 + k0 + 4);
        gload16(Bg0 + k0, BsW);
        gload16(Bg1 + k0, BsW + 512);
        uint4 pa, pc;
        pa.x = cvtpk(a0.x, a0.y); pa.y = cvtpk(a0.z, a0.w);
        pa.z = cvtpk(a1.x, a1.y); pa.w = cvtpk(a1.z, a1.w);
        pc.x = cvtpk(c0.x, c0.y); pc.y = cvtpk(c0.z, c0.w);
        pc.z = cvtpk(c1.x, c1.y); pc.w = cvtpk(c1.z, c1.w);
        *reinterpret_cast<uint4*>(&As[rowA0 * 32 + csA]) = pa;
        *reinterpret_cast<uint4*>(&As[rowA1 * 32 + csA]) = pc;
        __syncthreads();
        bf16x8 a[4], b[4];
        #pragma unroll
        for (int i = 0; i < 4; ++i)
            a[i] = *reinterpret_cast<const bf16x8*>(&As[(wr * 64 + i * 16 + r) * 32 + g * 8]);
        #pragma unroll
        for (int j = 0; j < 4; ++j)
            b[j] = *reinterpret_cast<const bf16x8*>(&Bs[(wc * 64 + j * 16 + r) * 32 + g * 8]);
        #pragma unroll
        for (int i = 0; i < 4; ++i)
            #pragma unroll
            for (int j = 0; j < 4; ++j)
                acc[i][j] = __builtin_amdgcn_mfma_f32_16x16x32_bf16(a[i], b[j], acc[i][j], 0, 0, 0);
        __syncthreads();
    }

    const bool isQ = (blockIdx.y < 2);
    #pragma unroll
    for (int i = 0; i < 4; ++i) {
        #pragma unroll
        for (int j = 0; j < 4; ++j) {
            long col = n0 + wc * 64 + j * 16 + r;
            #pragma unroll
            for (int e = 0; e < 4; ++e) {
                long row = m0 + wr * 64 + i * 16 + g * 4 + e;
                u16 v = f2bf(acc[i][j][e]);
                if (isQ) Qb[row * 256 + col] = v;
                else     KVb[row * 512 + col - 256] = v;
            }
        }
    }
}

// ---------------- MFMA GEMM (final): C f32 = A bf16 * BT^T ----------------
__global__ __launch_bounds__(256) void mfma_gemm(const u16* __restrict__ A,
                                                 const u16* __restrict__ BT,
                                                 float* __restrict__ C, int N) {
    __shared__ u16 As[4096];
    __shared__ u16 Bs[4096];
    const int t = threadIdx.x;
    const int w = t >> 6, lane = t & 63;
    const long m0 = (long)blockIdx.x * 128;
    const long n0 = (long)blockIdx.y * 128;
    const int wr = w >> 1, wc = w & 1;
    const int r = lane & 15, g = lane >> 4;

    f32x4 acc[4][4];
    #pragma unroll
    for (int i = 0; i < 4; ++i)
        #pragma unroll
        for (int j = 0; j < 4; ++j) acc[i][j] = (f32x4){0.f, 0.f, 0.f, 0.f};

    const int u0 = w * 128 + lane;
    const int row0 = u0 >> 2, cs0 = (u0 & 3) * 8;
    const int u1 = u0 + 64;
    const int row1 = u1 >> 2, cs1 = (u1 & 3) * 8;
    const u16* Ag0 = A + (m0 + row0) * 256 + cs0;
    const u16* Ag1 = A + (m0 + row1) * 256 + cs1;
    const u16* Bg0 = BT + (n0 + row0) * 256 + cs0;
    const u16* Bg1 = BT + (n0 + row1) * 256 + cs1;
    u16* AsW = &As[w * 1024];
    u16* BsW = &Bs[w * 1024];

    for (int k0 = 0; k0 < 256; k0 += 32) {
        gload16(Ag0 + k0, AsW);
        gload16(Ag1 + k0, AsW + 512);
        gload16(Bg0 + k0, BsW);
        gload16(Bg1 + k0, BsW + 512);
        __syncthreads();
        bf16x8 a[4], b[4];
        #pragma unroll
        for (int i = 0; i < 4; ++i)
            a[i] = *reinterpret_cast<const bf16x8*>(&As[(wr * 64 + i * 16 + r) * 32 + g * 8]);
        #pragma unroll
        for (int j = 0; j < 4; ++j)
            b[j] = *reinterpret_cast<const bf16x8*>(&Bs[(wc * 64 + j * 16 + r) * 32 + g * 8]);
        #pragma unroll
        for (int i = 0; i < 4; ++i)
            #pragma unroll
            for (int j = 0; j < 4; ++j)
                acc[i][j] = __builtin_amdgcn_mfma_f32_16x16x32_bf16(a[i], b[j], acc[i][j], 0, 0, 0);
        __syncthreads();
    }

    #pragma unroll
    for (int i = 0; i < 4; ++i)
        #pragma unroll
        for (int j = 0; j < 4; ++j)
            #pragma unroll
            for (int e = 0; e < 4; ++e) {
                long row = m0 + wr * 64 + i * 16 + g * 4 + e;
                long col = n0 + wc * 64 + j * 16 + r;
                C[row * N + col] = acc[i][j][e];
            }
}

// ---------------- MFMA Attention ----------------
// 4 waves, wave w owns q = w*16 + r. Augmented-K (rel folded into MFMA), swapped
// QK (lane holds S[k][q] in log2 domain), softmax: max3 + exp2 + 2 shfl. P packed
// bf16 -> LDS P^T (overlay on dead Ks/Qe) -> b128 B-frags for PV.
__global__ __launch_bounds__(256, 4) void attn_mfma(const u16* __restrict__ Qb,
                                                    const u16* __restrict__ KVb,
                                                    const u16* __restrict__ embT,
                                                    u16* __restrict__ Ob) {
    __shared__ __align__(16) char blob[26624];
    u16* Ks  = (u16*)blob;               // [144][64] swizzled: 0..31 K*s*l2e, 32..55 onehots, 56..63 zero
    u16* Qe  = (u16*)(blob + 18432);     // [64][32]: rel*log2e dims + zero tail
    u16* ehT = (u16*)(blob + 22528);     // [32][32] bf16, rows 0..22 valid
    u16* ewT = (u16*)(blob + 24576);     // [32][32]
    u16* PT  = (u16*)blob;               // [64][PT_S] overlay after QK
    __shared__ u16 Vt[32 * VT_S];        // V^T [d][k], swizzled, cols 144..159 zero

    const int gblk = blockIdx.x;
    const int n = gblk & 7;
    const int bx = (gblk >> 3) & 15;
    const int by = (gblk >> 7) & 15;
    const int b = gblk >> 11;
    const int t = threadIdx.x;
    const int w = t >> 6, lane = t & 63;
    const int g = lane >> 4, r = lane & 15;

    const int q = w * 16 + r;
    const int qi = q >> 3, qj = q & 7;
    const long qrow = ((long)b * 128 + by * 8 + qi) * 128 + bx * 8 + qj;

    bf16x8 qa1 = *reinterpret_cast<const bf16x8*>(Qb + qrow * 256 + n * 32 + g * 8);

    // ---- stage K (swizzled) / V^T (scatter) ----
    for (int u = t; u < NKEYS * 8; u += 256) {
        int kk = u >> 3, part = u & 7;
        int ky = kk / KVK, kx = kk - ky * KVK;
        int gy = by * 8 + ky - 2, gx = bx * 8 + kx - 2;
        uint4 val = make_uint4(0u, 0u, 0u, 0u);
        if ((unsigned)gy < 128u && (unsigned)gx < 128u) {
            long row = ((long)b * 128 + gy) * 128 + gx;
            val = *reinterpret_cast<const uint4*>(KVb + row * 512 + n * 64 + part * 8);
        }
        if (part < 4) {
            int col = (part * 8) ^ ((kk & 7) << 3);
            *reinterpret_cast<uint4*>(&Ks[kk * 64 + col]) = val;
        } else {
            int d0 = (part - 4) * 8;
            u16 tmp[8];
            *reinterpret_cast<uint4*>(tmp) = val;
            #pragma unroll
            for (int i = 0; i < 8; ++i) {
                int d = d0 + i;
                Vt[d * VT_S + (kk ^ (((d >> 3) & 3) << 3))] = tmp[i];
            }
        }
    }
    // ---- Ks ext cols zero ----
    for (int u = t; u < 576; u += 256) {
        int kk = u >> 2;
        int col = (32 + (u & 3) * 8) ^ ((kk & 7) << 3);
        *reinterpret_cast<uint4*>(&Ks[kk * 64 + col]) = make_uint4(0u, 0u, 0u, 0u);
    }
    if (t < 64) *reinterpret_cast<uint4*>(&Qe[t * 32 + 24]) = make_uint4(0u, 0u, 0u, 0u);
    if (t >= 224) {
        int d = t - 224;
        int sw = ((d >> 3) & 3) << 3;
        *reinterpret_cast<uint4*>(&Vt[d * VT_S + (144 ^ sw)]) = make_uint4(0u, 0u, 0u, 0u);
        *reinterpret_cast<uint4*>(&Vt[d * VT_S + (152 ^ sw)]) = make_uint4(0u, 0u, 0u, 0u);
    }
    // ---- pre-transposed embeddings: 1 uint4 per thread ----
    if (t < 184) {
        uint4 v = *reinterpret_cast<const uint4*>(embT + t * 8);
        u16* dst = (t < 92) ? (ehT + t * 8) : (ewT + t * 8 - 736);
        *reinterpret_cast<uint4*>(dst) = v;
    }
    __syncthreads();

    // ---- phase 1: rel-MFMA -> Qe ext dims (x log2e); one-hots into Ks ----
    {
        bf16x8 ah0 = *reinterpret_cast<const bf16x8*>(&ehT[r * 32 + g * 8]);
        bf16x8 ah1 = *reinterpret_cast<const bf16x8*>(&ehT[(16 + r) * 32 + g * 8]);
        bf16x8 aw0 = *reinterpret_cast<const bf16x8*>(&ewT[r * 32 + g * 8]);
        bf16x8 aw1 = *reinterpret_cast<const bf16x8*>(&ewT[(16 + r) * 32 + g * 8]);
        f32x4 z = (f32x4){0.f, 0.f, 0.f, 0.f};
        f32x4 rh0 = __builtin_amdgcn_mfma_f32_16x16x32_bf16(ah0, qa1, z, 0, 0, 0);
        f32x4 rh1 = __builtin_amdgcn_mfma_f32_16x16x32_bf16(ah1, qa1, z, 0, 0, 0);
        f32x4 rw0 = __builtin_amdgcn_mfma_f32_16x16x32_bf16(aw0, qa1, z, 0, 0, 0);
        f32x4 rw1 = __builtin_amdgcn_mfma_f32_16x16x32_bf16(aw1, qa1, z, 0, 0, 0);
        #pragma unroll
        for (int ti = 0; ti < 2; ++ti) {
            #pragma unroll
            for (int e = 0; e < 4; ++e) {
                int p = ti * 16 + g * 4 + e;
                float vh = (ti ? rh1[e] : rh0[e]) * LOG2E;
                float vw = (ti ? rw1[e] : rw0[e]) * LOG2E;
                int kyd = p + qi - 11;
                int kxd = p + qj - 11;
                if ((unsigned)kyd < 12u) Qe[q * 32 + kyd] = f2bf(vh);
                if ((unsigned)kxd < 12u) Qe[q * 32 + 12 + kxd] = f2bf(vw);
            }
        }
        if (t < NKEYS) {
            int ky = (t * 171) >> 11;
            int kx = t - 12 * ky;
            int sw = (t & 7) << 3;
            Ks[t * 64 + ((32 + ky) ^ sw)] = 0x3F80;  // bf16 1.0
            Ks[t * 64 + ((44 + kx) ^ sw)] = 0x3F80;
        }
    }
    __syncthreads();

    // ---- phase 2: augmented QK^T (swapped): acc[j][e] = log2-score[16j+4g+e][q] ----
    bf16x8 qa2 = *reinterpret_cast<const bf16x8*>(&Qe[q * 32 + g * 8]);
    f32x4 acc[9];
    #pragma unroll
    for (int j = 0; j < 9; ++j) {
        int krow = j * 16 + r;
        int sw = (r & 7) << 3;
        bf16x8 kb0 = *reinterpret_cast<const bf16x8*>(&Ks[krow * 64 + ((g * 8) ^ sw)]);
        bf16x8 kb1 = *reinterpret_cast<const bf16x8*>(&Ks[krow * 64 + ((32 + g * 8) ^ sw)]);
        f32x4 z = (f32x4){0.f, 0.f, 0.f, 0.f};
        acc[j] = __builtin_amdgcn_mfma_f32_16x16x32_bf16(kb1, qa2,
                 __builtin_amdgcn_mfma_f32_16x16x32_bf16(kb0, qa1, z, 0, 0, 0), 0, 0, 0);
    }

    // ---- softmax (log2 domain, register-only) ----
    float mx = max3f(acc[0][0], acc[0][1], acc[0][2]);
    mx = fmaxf(mx, acc[0][3]);
    #pragma unroll
    for (int j = 1; j < 9; ++j)
        mx = max3f(mx, max3f(acc[j][0], acc[j][1], acc[j][2]), acc[j][3]);
    mx = fmaxf(mx, __shfl_xor(mx, 16));
    mx = fmaxf(mx, __shfl_xor(mx, 32));
    float s0 = 0.f, s1 = 0.f, s2 = 0.f, s3 = 0.f;
    u32 pkA[9], pkB[9];
    #pragma unroll
    for (int j = 0; j < 9; ++j) {
        float e0 = exp2a(acc[j][0] - mx);
        float e1 = exp2a(acc[j][1] - mx);
        float e2 = exp2a(acc[j][2] - mx);
        float e3 = exp2a(acc[j][3] - mx);
        s0 += e0; s1 += e1; s2 += e2; s3 += e3;
        pkA[j] = cvtpk(e0, e1);
        pkB[j] = cvtpk(e2, e3);
    }
    float sum = (s0 + s1) + (s2 + s3);
    sum += __shfl_xor(sum, 16);
    sum += __shfl_xor(sum, 32);
    const float inv = __builtin_amdgcn_rcpf(sum);

    __syncthreads();   // Ks/Qe dead -> PT overlays

    // ---- write P^T[q][k] (packed u32 pairs) + zero pad cols ----
    {
        const int ptb = q * PT_S;
        #pragma unroll
        for (int j = 0; j < 9; ++j) {
            *reinterpret_cast<u32*>(&PT[ptb + 16 * j + 4 * g]) = pkA[j];
            *reinterpret_cast<u32*>(&PT[ptb + 16 * j + 4 * g + 2]) = pkB[j];
        }
    }
    if (t < 64) {
        *reinterpret_cast<uint4*>(&PT[t * PT_S + 144]) = make_uint4(0u, 0u, 0u, 0u);
        *reinterpret_cast<uint4*>(&PT[t * PT_S + 152]) = make_uint4(0u, 0u, 0u, 0u);
    }
    __syncthreads();

    // ---- PV: A = V^T frags, B = P^T frags; 5 K-slices ----
    const int sw0 = (r >> 3) << 3;
    const int sw1 = (2 + (r >> 3)) << 3;
    f32x4 o0 = (f32x4){0.f, 0.f, 0.f, 0.f};
    f32x4 o1 = (f32x4){0.f, 0.f, 0.f, 0.f};
    #pragma unroll
    for (int kk = 0; kk < 5; ++kk) {
        bf16x8 pb = *reinterpret_cast<const bf16x8*>(&PT[q * PT_S + kk * 32 + g * 8]);
        bf16x8 va0 = *reinterpret_cast<const bf16x8*>(&Vt[r * VT_S + ((kk * 32 + g * 8) ^ sw0)]);
        bf16x8 va1 = *reinterpret_cast<const bf16x8*>(&Vt[(16 + r) * VT_S + ((kk * 32 + g * 8) ^ sw1)]);
        o0 = __builtin_amdgcn_mfma_f32_16x16x32_bf16(va0, pb, o0, 0, 0, 0);
        o1 = __builtin_amdgcn_mfma_f32_16x16x32_bf16(va1, pb, o1, 0, 0, 0);
    }
    {
        uint2 st0, st1;
        st0.x = cvtpk(o0[0] * inv, o0[1] * inv);
        st0.y = cvtpk(o0[2] * inv, o0[3] * inv);
        st1.x = cvtpk(o1[0] * inv, o1[1] * inv);
        st1.y = cvtpk(o1[2] * inv, o1[3] * inv);
        *reinterpret_cast<uint2*>(Ob + qrow * 256 + n * 32 + g * 4) = st0;
        *reinterpret_cast<uint2*>(Ob + qrow * 256 + n * 32 + 16 + g * 4) = st1;
    }
}

extern "C" void kernel_launch(void* const* d_in, const int* in_sizes, int n_in,
                              void* d_out, int out_size, void* d_ws, size_t ws_size,
                              hipStream_t stream) {
    const float* x     = (const float*)d_in[0];
    const float* w_q   = (const float*)d_in[1];
    const float* w_kv  = (const float*)d_in[2];
    const float* w_out = (const float*)d_in[3];
    const float* emb_h = (const float*)d_in[4];
    const float* emb_w = (const float*)d_in[5];

    u16* Qb = (u16*)d_out;                               // 32MB, dead before final gemm
    char* ws = (char*)d_ws;
    u16* KVb   = (u16*)(ws);                             // 64MB
    u16* Ob    = (u16*)(ws + (size_t)67108864);          // 32MB
    u16* wT    = (u16*)(ws + (size_t)100663296);         // [768][256] bf16 = 384KB
    u16* woutT = (u16*)(ws + (size_t)100663296 + 393216);// 128KB
    u16* embT  = (u16*)(ws + (size_t)100663296 + 524288);// 1472 u16

    dim3 blk(256);
    prep_weights<<<dim3(1026), blk, 0, stream>>>(w_q, w_kv, w_out, wT, woutT, emb_h, emb_w, embT);
    gemm_qkv<<<dim3(512, 6), blk, 0, stream>>>(x, wT, Qb, KVb);
    attn_mfma<<<dim3(8192), blk, 0, stream>>>(Qb, KVb, embT, Ob);
    mfma_gemm<<<dim3(512, 2), blk, 0, stream>>>(Ob, woutT, (float*)d_out, 256);
}

// Round 8
// 141.141 us; speedup vs baseline: 8.0614x; 1.1396x over previous
//
#include <hip/hip_runtime.h>
#include <hip/hip_bf16.h>
#include <cstdint>

// HaloAttention: B=4, H=W=128, C=256, 8 heads, kd=32, block=8, halo=2, kvk=12.
// prep_weights (W^T bf16, K pre-scaled by log2e/sqrt(32), emb^T bf16) ->
// gemm_qkv (x panel LDS-resident, read once; 6 col-tiles) -> attn (augmented-K,
// log2-domain softmax, LDS P^T) -> gemm out.

#define KVK 12
#define NKEYS 144
#define VT_S 160
#define PT_S 168
#define LOG2E 1.4426950408889634f

typedef unsigned int u32;
typedef unsigned short u16;
typedef __attribute__((ext_vector_type(8))) __bf16 bf16x8;
typedef __attribute__((ext_vector_type(4))) float f32x4;

__device__ __forceinline__ u16 f2bf(float f) {
    u32 x = __float_as_uint(f);
    return (u16)((x + 0x7fffu + ((x >> 16) & 1u)) >> 16);
}
__device__ __forceinline__ u32 cvtpk(float lo, float hi) {
    u32 d;
    asm("v_cvt_pk_bf16_f32 %0, %1, %2" : "=v"(d) : "v"(lo), "v"(hi));
    return d;
}
__device__ __forceinline__ float max3f(float a, float b, float c) {
    float d;
    asm("v_max3_f32 %0, %1, %2, %3" : "=v"(d) : "v"(a), "v"(b), "v"(c));
    return d;
}
__device__ __forceinline__ float exp2a(float x) {
    float d;
    asm("v_exp_f32 %0, %1" : "=v"(d) : "v"(x));
    return d;
}
__device__ __forceinline__ void gload16(const void* g, void* l) {
    __builtin_amdgcn_global_load_lds(
        (const __attribute__((address_space(1))) void*)g,
        (__attribute__((address_space(3))) void*)l, 16, 0, 0);
}

// ---------------- prep: W^T bf16 (K pre-scaled), emb^T bf16 ----------------
__global__ __launch_bounds__(256) void prep_weights(const float* __restrict__ wq,
                                                    const float* __restrict__ wkv,
                                                    const float* __restrict__ wout,
                                                    u16* __restrict__ wT,
                                                    u16* __restrict__ woutT,
                                                    const float* __restrict__ emb_h,
                                                    const float* __restrict__ emb_w,
                                                    u16* __restrict__ embT) {
    int blk = blockIdx.x, t = threadIdx.x;
    if (blk < 256) {
        int idx = blk * 256 + t; int nn = idx >> 8, k = idx & 255;
        wT[idx] = f2bf(wq[(long)k * 256 + nn]);
    } else if (blk < 768) {
        int idx = (blk - 256) * 256 + t; int nn = idx >> 8, k = idx & 255;
        float v = wkv[(long)k * 512 + nn];
        if ((nn & 32) == 0) v *= 0.2550348642f;  // (1/sqrt(32)) * log2(e)
        wT[65536 + idx] = f2bf(v);
    } else if (blk < 1024) {
        int idx = (blk - 768) * 256 + t; int nn = idx >> 8, k = idx & 255;
        woutT[idx] = f2bf(wout[(long)k * 256 + nn]);
    } else if (blk == 1024) {
        for (int i = t; i < 736; i += 256) {
            int p = i >> 5, d = i & 31;
            embT[i] = f2bf(emb_h[d * 23 + p]);
        }
    } else {
        for (int i = t; i < 736; i += 256) {
            int p = i >> 5, d = i & 31;
            embT[736 + i] = f2bf(emb_w[d * 23 + p]);
        }
    }
}

// ------------- fused QKV GEMM: x panel (128x256) LDS-resident, 6 col tiles -----
// Apan swizzled: 16B unit u (0..31) stored at u ^ (row & 7); b128 reads uniform
// across banks. B tiles staged per K-step via global_load_lds (WT is L2-resident).
__global__ __launch_bounds__(256) void gemm_qkv(const float* __restrict__ X,
                                                const u16* __restrict__ WT,
                                                u16* __restrict__ Qb,
                                                u16* __restrict__ KVb) {
    __shared__ u16 Apan[128 * 256];   // 64 KB
    __shared__ u16 Bs[4096];          // 8 KB
    const int t = threadIdx.x;
    const int w = t >> 6, lane = t & 63;
    const long m0 = (long)blockIdx.x * 128;
    const int wr = w >> 1, wc = w & 1;
    const int r = lane & 15, g = lane >> 4;

    // ---- phase 0: x f32 -> bf16 -> swizzled LDS panel (x strip is linear) ----
    #pragma unroll
    for (int i = 0; i < 16; ++i) {
        int v = i * 256 + t;
        int row = v >> 5, u = v & 31;
        const float* src = X + (m0 + row) * 256 + u * 8;
        float4 f0 = *reinterpret_cast<const float4*>(src);
        float4 f1 = *reinterpret_cast<const float4*>(src + 4);
        uint4 pk;
        pk.x = cvtpk(f0.x, f0.y); pk.y = cvtpk(f0.z, f0.w);
        pk.z = cvtpk(f1.x, f1.y); pk.w = cvtpk(f1.z, f1.w);
        *reinterpret_cast<uint4*>(&Apan[row * 256 + ((u ^ (row & 7)) << 3)]) = pk;
    }

    const int u0 = w * 128 + lane;
    const int rowB0 = u0 >> 2, csB0 = (u0 & 3) * 8;
    const int u1 = u0 + 64;
    const int rowB1 = u1 >> 2, csB1 = (u1 & 3) * 8;
    u16* BsW = &Bs[w * 1024];

    for (int nt = 0; nt < 6; ++nt) {
        const long n0 = nt * 128;
        const u16* Bg0 = WT + (n0 + rowB0) * 256 + csB0;
        const u16* Bg1 = WT + (n0 + rowB1) * 256 + csB1;

        f32x4 acc[4][4];
        #pragma unroll
        for (int i = 0; i < 4; ++i)
            #pragma unroll
            for (int j = 0; j < 4; ++j) acc[i][j] = (f32x4){0.f, 0.f, 0.f, 0.f};

        for (int k0 = 0; k0 < 256; k0 += 32) {
            gload16(Bg0 + k0, BsW);
            gload16(Bg1 + k0, BsW + 512);
            __syncthreads();
            bf16x8 a[4], b[4];
            const int cu = k0 >> 3;
            #pragma unroll
            for (int i = 0; i < 4; ++i) {
                int row = wr * 64 + i * 16 + r;
                a[i] = *reinterpret_cast<const bf16x8*>(
                    &Apan[row * 256 + (((cu + g) ^ (row & 7)) << 3)]);
            }
            #pragma unroll
            for (int j = 0; j < 4; ++j)
                b[j] = *reinterpret_cast<const bf16x8*>(&Bs[(wc * 64 + j * 16 + r) * 32 + g * 8]);
            #pragma unroll
            for (int i = 0; i < 4; ++i)
                #pragma unroll
                for (int j = 0; j < 4; ++j)
                    acc[i][j] = __builtin_amdgcn_mfma_f32_16x16x32_bf16(a[i], b[j], acc[i][j], 0, 0, 0);
            __syncthreads();
        }

        const bool isQ = (nt < 2);
        #pragma unroll
        for (int i = 0; i < 4; ++i) {
            #pragma unroll
            for (int j = 0; j < 4; ++j) {
                long col = n0 + wc * 64 + j * 16 + r;
                #pragma unroll
                for (int e = 0; e < 4; ++e) {
                    long row = m0 + wr * 64 + i * 16 + g * 4 + e;
                    u16 v = f2bf(acc[i][j][e]);
                    if (isQ) Qb[row * 256 + col] = v;
                    else     KVb[row * 512 + col - 256] = v;
                }
            }
        }
    }
}

// ---------------- MFMA GEMM (final): C f32 = A bf16 * BT^T ----------------
__global__ __launch_bounds__(256) void mfma_gemm(const u16* __restrict__ A,
                                                 const u16* __restrict__ BT,
                                                 float* __restrict__ C, int N) {
    __shared__ u16 As[4096];
    __shared__ u16 Bs[4096];
    const int t = threadIdx.x;
    const int w = t >> 6, lane = t & 63;
    const long m0 = (long)blockIdx.x * 128;
    const long n0 = (long)blockIdx.y * 128;
    const int wr = w >> 1, wc = w & 1;
    const int r = lane & 15, g = lane >> 4;

    f32x4 acc[4][4];
    #pragma unroll
    for (int i = 0; i < 4; ++i)
        #pragma unroll
        for (int j = 0; j < 4; ++j) acc[i][j] = (f32x4){0.f, 0.f, 0.f, 0.f};

    const int u0 = w * 128 + lane;
    const int row0 = u0 >> 2, cs0 = (u0 & 3) * 8;
    const int u1 = u0 + 64;
    const int row1 = u1 >> 2, cs1 = (u1 & 3) * 8;
    const u16* Ag0 = A + (m0 + row0) * 256 + cs0;
    const u16* Ag1 = A + (m0 + row1) * 256 + cs1;
    const u16* Bg0 = BT + (n0 + row0) * 256 + cs0;
    const u16* Bg1 = BT + (n0 + row1) * 256 + cs1;
    u16* AsW = &As[w * 1024];
    u16* BsW = &Bs[w * 1024];

    for (int k0 = 0; k0 < 256; k0 += 32) {
        gload16(Ag0 + k0, AsW);
        gload16(Ag1 + k0, AsW + 512);
        gload16(Bg0 + k0, BsW);
        gload16(Bg1 + k0, BsW + 512);
        __syncthreads();
        bf16x8 a[4], b[4];
        #pragma unroll
        for (int i = 0; i < 4; ++i)
            a[i] = *reinterpret_cast<const bf16x8*>(&As[(wr * 64 + i * 16 + r) * 32 + g * 8]);
        #pragma unroll
        for (int j = 0; j < 4; ++j)
            b[j] = *reinterpret_cast<const bf16x8*>(&Bs[(wc * 64 + j * 16 + r) * 32 + g * 8]);
        #pragma unroll
        for (int i = 0; i < 4; ++i)
            #pragma unroll
            for (int j = 0; j < 4; ++j)
                acc[i][j] = __builtin_amdgcn_mfma_f32_16x16x32_bf16(a[i], b[j], acc[i][j], 0, 0, 0);
        __syncthreads();
    }

    #pragma unroll
    for (int i = 0; i < 4; ++i)
        #pragma unroll
        for (int j = 0; j < 4; ++j)
            #pragma unroll
            for (int e = 0; e < 4; ++e) {
                long row = m0 + wr * 64 + i * 16 + g * 4 + e;
                long col = n0 + wc * 64 + j * 16 + r;
                C[row * N + col] = acc[i][j][e];
            }
}

// ---------------- MFMA Attention ----------------
// 4 waves, wave w owns q = w*16 + r. Augmented-K (rel folded into MFMA), swapped
// QK (lane holds S[k][q] in log2 domain), softmax: max3 + exp2 + 2 shfl. P packed
// bf16 -> LDS P^T (overlay on dead Ks/Qe) -> b128 B-frags for PV.
__global__ __launch_bounds__(256, 4) void attn_mfma(const u16* __restrict__ Qb,
                                                    const u16* __restrict__ KVb,
                                                    const u16* __restrict__ embT,
                                                    u16* __restrict__ Ob) {
    __shared__ __align__(16) char blob[26624];
    u16* Ks  = (u16*)blob;               // [144][64] swizzled
    u16* Qe  = (u16*)(blob + 18432);     // [64][32]
    u16* ehT = (u16*)(blob + 22528);     // [32][32]
    u16* ewT = (u16*)(blob + 24576);     // [32][32]
    u16* PT  = (u16*)blob;               // [64][PT_S] overlay after QK
    __shared__ u16 Vt[32 * VT_S];        // V^T [d][k], swizzled, cols 144..159 zero

    const int gblk = blockIdx.x;
    const int n = gblk & 7;
    const int bx = (gblk >> 3) & 15;
    const int by = (gblk >> 7) & 15;
    const int b = gblk >> 11;
    const int t = threadIdx.x;
    const int w = t >> 6, lane = t & 63;
    const int g = lane >> 4, r = lane & 15;

    const int q = w * 16 + r;
    const int qi = q >> 3, qj = q & 7;
    const long qrow = ((long)b * 128 + by * 8 + qi) * 128 + bx * 8 + qj;

    bf16x8 qa1 = *reinterpret_cast<const bf16x8*>(Qb + qrow * 256 + n * 32 + g * 8);

    // ---- stage K (swizzled) / V^T (scatter) ----
    for (int u = t; u < NKEYS * 8; u += 256) {
        int kk = u >> 3, part = u & 7;
        int ky = kk / KVK, kx = kk - ky * KVK;
        int gy = by * 8 + ky - 2, gx = bx * 8 + kx - 2;
        uint4 val = make_uint4(0u, 0u, 0u, 0u);
        if ((unsigned)gy < 128u && (unsigned)gx < 128u) {
            long row = ((long)b * 128 + gy) * 128 + gx;
            val = *reinterpret_cast<const uint4*>(KVb + row * 512 + n * 64 + part * 8);
        }
        if (part < 4) {
            int col = (part * 8) ^ ((kk & 7) << 3);
            *reinterpret_cast<uint4*>(&Ks[kk * 64 + col]) = val;
        } else {
            int d0 = (part - 4) * 8;
            u16 tmp[8];
            *reinterpret_cast<uint4*>(tmp) = val;
            #pragma unroll
            for (int i = 0; i < 8; ++i) {
                int d = d0 + i;
                Vt[d * VT_S + (kk ^ (((d >> 3) & 3) << 3))] = tmp[i];
            }
        }
    }
    // ---- Ks ext cols zero ----
    for (int u = t; u < 576; u += 256) {
        int kk = u >> 2;
        int col = (32 + (u & 3) * 8) ^ ((kk & 7) << 3);
        *reinterpret_cast<uint4*>(&Ks[kk * 64 + col]) = make_uint4(0u, 0u, 0u, 0u);
    }
    if (t < 64) *reinterpret_cast<uint4*>(&Qe[t * 32 + 24]) = make_uint4(0u, 0u, 0u, 0u);
    if (t >= 224) {
        int d = t - 224;
        int sw = ((d >> 3) & 3) << 3;
        *reinterpret_cast<uint4*>(&Vt[d * VT_S + (144 ^ sw)]) = make_uint4(0u, 0u, 0u, 0u);
        *reinterpret_cast<uint4*>(&Vt[d * VT_S + (152 ^ sw)]) = make_uint4(0u, 0u, 0u, 0u);
    }
    // ---- pre-transposed embeddings: 1 uint4 per thread ----
    if (t < 184) {
        uint4 v = *reinterpret_cast<const uint4*>(embT + t * 8);
        u16* dst = (t < 92) ? (ehT + t * 8) : (ewT + t * 8 - 736);
        *reinterpret_cast<uint4*>(dst) = v;
    }
    __syncthreads();

    // ---- phase 1: rel-MFMA -> Qe ext dims (x log2e); one-hots into Ks ----
    {
        bf16x8 ah0 = *reinterpret_cast<const bf16x8*>(&ehT[r * 32 + g * 8]);
        bf16x8 ah1 = *reinterpret_cast<const bf16x8*>(&ehT[(16 + r) * 32 + g * 8]);
        bf16x8 aw0 = *reinterpret_cast<const bf16x8*>(&ewT[r * 32 + g * 8]);
        bf16x8 aw1 = *reinterpret_cast<const bf16x8*>(&ewT[(16 + r) * 32 + g * 8]);
        f32x4 z = (f32x4){0.f, 0.f, 0.f, 0.f};
        f32x4 rh0 = __builtin_amdgcn_mfma_f32_16x16x32_bf16(ah0, qa1, z, 0, 0, 0);
        f32x4 rh1 = __builtin_amdgcn_mfma_f32_16x16x32_bf16(ah1, qa1, z, 0, 0, 0);
        f32x4 rw0 = __builtin_amdgcn_mfma_f32_16x16x32_bf16(aw0, qa1, z, 0, 0, 0);
        f32x4 rw1 = __builtin_amdgcn_mfma_f32_16x16x32_bf16(aw1, qa1, z, 0, 0, 0);
        #pragma unroll
        for (int ti = 0; ti < 2; ++ti) {
            #pragma unroll
            for (int e = 0; e < 4; ++e) {
                int p = ti * 16 + g * 4 + e;
                float vh = (ti ? rh1[e] : rh0[e]) * LOG2E;
                float vw = (ti ? rw1[e] : rw0[e]) * LOG2E;
                int kyd = p + qi - 11;
                int kxd = p + qj - 11;
                if ((unsigned)kyd < 12u) Qe[q * 32 + kyd] = f2bf(vh);
                if ((unsigned)kxd < 12u) Qe[q * 32 + 12 + kxd] = f2bf(vw);
            }
        }
        if (t < NKEYS) {
            int ky = (t * 171) >> 11;
            int kx = t - 12 * ky;
            int sw = (t & 7) << 3;
            Ks[t * 64 + ((32 + ky) ^ sw)] = 0x3F80;  // bf16 1.0
            Ks[t * 64 + ((44 + kx) ^ sw)] = 0x3F80;
        }
    }
    __syncthreads();

    // ---- phase 2: augmented QK^T (swapped): acc[j][e] = log2-score[16j+4g+e][q] ----
    bf16x8 qa2 = *reinterpret_cast<const bf16x8*>(&Qe[q * 32 + g * 8]);
    f32x4 acc[9];
    #pragma unroll
    for (int j = 0; j < 9; ++j) {
        int krow = j * 16 + r;
        int sw = (r & 7) << 3;
        bf16x8 kb0 = *reinterpret_cast<const bf16x8*>(&Ks[krow * 64 + ((g * 8) ^ sw)]);
        bf16x8 kb1 = *reinterpret_cast<const bf16x8*>(&Ks[krow * 64 + ((32 + g * 8) ^ sw)]);
        f32x4 z = (f32x4){0.f, 0.f, 0.f, 0.f};
        acc[j] = __builtin_amdgcn_mfma_f32_16x16x32_bf16(kb1, qa2,
                 __builtin_amdgcn_mfma_f32_16x16x32_bf16(kb0, qa1, z, 0, 0, 0), 0, 0, 0);
    }

    // ---- softmax (log2 domain, register-only) ----
    float mx = max3f(acc[0][0], acc[0][1], acc[0][2]);
    mx = fmaxf(mx, acc[0][3]);
    #pragma unroll
    for (int j = 1; j < 9; ++j)
        mx = max3f(mx, max3f(acc[j][0], acc[j][1], acc[j][2]), acc[j][3]);
    mx = fmaxf(mx, __shfl_xor(mx, 16));
    mx = fmaxf(mx, __shfl_xor(mx, 32));
    float s0 = 0.f, s1 = 0.f, s2 = 0.f, s3 = 0.f;
    u32 pkA[9], pkB[9];
    #pragma unroll
    for (int j = 0; j < 9; ++j) {
        float e0 = exp2a(acc[j][0] - mx);
        float e1 = exp2a(acc[j][1] - mx);
        float e2 = exp2a(acc[j][2] - mx);
        float e3 = exp2a(acc[j][3] - mx);
        s0 += e0; s1 += e1; s2 += e2; s3 += e3;
        pkA[j] = cvtpk(e0, e1);
        pkB[j] = cvtpk(e2, e3);
    }
    float sum = (s0 + s1) + (s2 + s3);
    sum += __shfl_xor(sum, 16);
    sum += __shfl_xor(sum, 32);
    const float inv = __builtin_amdgcn_rcpf(sum);

    __syncthreads();   // Ks/Qe dead -> PT overlays

    // ---- write P^T[q][k] (packed u32 pairs) + zero pad cols ----
    {
        const int ptb = q * PT_S;
        #pragma unroll
        for (int j = 0; j < 9; ++j) {
            *reinterpret_cast<u32*>(&PT[ptb + 16 * j + 4 * g]) = pkA[j];
            *reinterpret_cast<u32*>(&PT[ptb + 16 * j + 4 * g + 2]) = pkB[j];
        }
    }
    if (t < 64) {
        *reinterpret_cast<uint4*>(&PT[t * PT_S + 144]) = make_uint4(0u, 0u, 0u, 0u);
        *reinterpret_cast<uint4*>(&PT[t * PT_S + 152]) = make_uint4(0u, 0u, 0u, 0u);
    }
    __syncthreads();

    // ---- PV: A = V^T frags, B = P^T frags; 5 K-slices ----
    const int sw0 = (r >> 3) << 3;
    const int sw1 = (2 + (r >> 3)) << 3;
    f32x4 o0 = (f32x4){0.f, 0.f, 0.f, 0.f};
    f32x4 o1 = (f32x4){0.f, 0.f, 0.f, 0.f};
    #pragma unroll
    for (int kk = 0; kk < 5; ++kk) {
        bf16x8 pb = *reinterpret_cast<const bf16x8*>(&PT[q * PT_S + kk * 32 + g * 8]);
        bf16x8 va0 = *reinterpret_cast<const bf16x8*>(&Vt[r * VT_S + ((kk * 32 + g * 8) ^ sw0)]);
        bf16x8 va1 = *reinterpret_cast<const bf16x8*>(&Vt[(16 + r) * VT_S + ((kk * 32 + g * 8) ^ sw1)]);
        o0 = __builtin_amdgcn_mfma_f32_16x16x32_bf16(va0, pb, o0, 0, 0, 0);
        o1 = __builtin_amdgcn_mfma_f32_16x16x32_bf16(va1, pb, o1, 0, 0, 0);
    }
    {
        uint2 st0, st1;
        st0.x = cvtpk(o0[0] * inv, o0[1] * inv);
        st0.y = cvtpk(o0[2] * inv, o0[3] * inv);
        st1.x = cvtpk(o1[0] * inv, o1[1] * inv);
        st1.y = cvtpk(o1[2] * inv, o1[3] * inv);
        *reinterpret_cast<uint2*>(Ob + qrow * 256 + n * 32 + g * 4) = st0;
        *reinterpret_cast<uint2*>(Ob + qrow * 256 + n * 32 + 16 + g * 4) = st1;
    }
}

extern "C" void kernel_launch(void* const* d_in, const int* in_sizes, int n_in,
                              void* d_out, int out_size, void* d_ws, size_t ws_size,
                              hipStream_t stream) {
    const float* x     = (const float*)d_in[0];
    const float* w_q   = (const float*)d_in[1];
    const float* w_kv  = (const float*)d_in[2];
    const float* w_out = (const float*)d_in[3];
    const float* emb_h = (const float*)d_in[4];
    const float* emb_w = (const float*)d_in[5];

    u16* Qb = (u16*)d_out;                               // 32MB, dead before final gemm
    char* ws = (char*)d_ws;
    u16* KVb   = (u16*)(ws);                             // 64MB
    u16* Ob    = (u16*)(ws + (size_t)67108864);          // 32MB
    u16* wT    = (u16*)(ws + (size_t)100663296);         // [768][256] bf16 = 384KB
    u16* woutT = (u16*)(ws + (size_t)100663296 + 393216);// 128KB
    u16* embT  = (u16*)(ws + (size_t)100663296 + 524288);// 1472 u16

    dim3 blk(256);
    prep_weights<<<dim3(1026), blk, 0, stream>>>(w_q, w_kv, w_out, wT, woutT, emb_h, emb_w, embT);
    gemm_qkv<<<dim3(512), blk, 0, stream>>>(x, wT, Qb, KVb);
    attn_mfma<<<dim3(8192), blk, 0, stream>>>(Qb, KVb, embT, Ob);
    mfma_gemm<<<dim3(512, 2), blk, 0, stream>>>(Ob, woutT, (float*)d_out, 256);
}